// Round 15
// baseline (738.055 us; speedup 1.0000x reference)
//
#include <hip/hip_runtime.h>
#include <hip/hip_bf16.h>

using bf16 = __hip_bfloat16;

constexpr int NE  = 50000;   // entities
constexpr int H   = 200;     // hidden dim
constexpr int R2C = 500;     // 2*num_rels
constexpr int TS  = 4;       // timesteps
constexpr int EC  = 400000;  // edges per step
constexpr float SLOPE = 0.22916666666666666f;  // rrelu eval slope
constexpr int NSCAN = (NE + 255) / 256;        // 196

// node-GEMM MFMA geometry
constexpr int KP = 224;      // K padded to 7*32
constexpr int KS = 7;        // k-steps of 32
constexpr int NT = 13;       // n-tiles of 16

// GRU-GEMM MFMA geometry (out [512][608])
constexpr int GNT = 38;      // n-tiles (608/16)
constexpr int GKI = 13;      // k-steps for W_ih (416/32)
constexpr int GKH = 7;       // k-steps for W_hh (224/32)
constexpr int GR  = 512;     // padded relation rows
constexpr int GCS = 608;     // padded gate cols (stride)

constexpr int RCH = 64;      // edges per block in k_relsums (round-11 structure)
constexpr int NRNG = 8;      // dst ranges (≈ XCD count); NE/NRNG = 6250
constexpr int DRNG = NE / NRNG;              // 6250
constexpr int SCHK = 1024;   // edges per scatter chunk
constexpr int NCHK = (EC + SCHK - 1) / SCHK; // 391

#define DEVINL __device__ __forceinline__

typedef __bf16 bf16x8v __attribute__((ext_vector_type(8)));
typedef float  f32x4   __attribute__((ext_vector_type(4)));

DEVINL float b2f(bf16 v) { return __bfloat162float(v); }
DEVINL bf16  f2b(float v) { return __float2bfloat16(v); }
DEVINL unsigned short f2bu(float x) { bf16 b = f2b(x); return *reinterpret_cast<unsigned short*>(&b); }
DEVINL float u2f(unsigned short u) { unsigned int w = (unsigned int)u << 16; float f; __builtin_memcpy(&f, &w, 4); return f; }

DEVINL float wave_sum(float v) {
  #pragma unroll
  for (int o = 32; o > 0; o >>= 1) v += __shfl_xor(v, o, 64);
  return v;
}

DEVINL float sigmoidf(float x) { return 1.0f / (1.0f + expf(-x)); }

// ---------------- init: l2norm rows of dynamic_emb -> h (f32) AND hb0 (bf16 padded) ----------------
__global__ __launch_bounds__(256) void k_init_h(const float* __restrict__ de,
                                                float* __restrict__ h,
                                                unsigned short* __restrict__ hb0) {
  int wid = threadIdx.x >> 6, lane = threadIdx.x & 63;
  int row = blockIdx.x * 4 + wid;
  if (row >= NE) return;
  int d0 = lane * 4;
  bool act = d0 < H;
  float4 v = make_float4(0.f, 0.f, 0.f, 0.f);
  if (act) v = *reinterpret_cast<const float4*>(de + (size_t)row * H + d0);
  float ss = v.x * v.x + v.y * v.y + v.z * v.z + v.w * v.w;
  ss = wave_sum(ss);
  float sc = 1.0f / fmaxf(sqrtf(ss), 1e-12f);
  if (act) {
    float4 o = make_float4(v.x * sc, v.y * sc, v.z * sc, v.w * sc);
    *reinterpret_cast<float4*>(h + (size_t)row * H + d0) = o;
    ushort4 ob; ob.x = f2bu(o.x); ob.y = f2bu(o.y); ob.z = f2bu(o.z); ob.w = f2bu(o.w);
    *reinterpret_cast<ushort4*>(hb0 + (size_t)row * KP + d0) = ob;
  } else if (d0 < KP) {
    ushort4 z; z.x = z.y = z.z = z.w = 0;
    *reinterpret_cast<ushort4*>(hb0 + (size_t)row * KP + d0) = z;
  }
}

__global__ __launch_bounds__(256) void k_init_h0(const float* er, float* h0) {
  int i = blockIdx.x * 256 + threadIdx.x;
  if (i < R2C * H) h0[i] = er[i];
}

// relWb = bf16(emb_rel @ W_n)   [R2C, H]
__global__ __launch_bounds__(256) void k_relw(const float* er, const float* wn,
                                              unsigned short* relWb) {
  __shared__ float a[H];
  int r = blockIdx.x;
  for (int d = threadIdx.x; d < H; d += 256) a[d] = er[r * H + d];
  __syncthreads();
  for (int c = threadIdx.x; c < H; c += 256) {
    float s = 0.f;
    for (int k = 0; k < H; k++) s += a[k] * wn[k * H + c];
    relWb[r * H + c] = f2bu(s);
  }
}

// pack Wn and Tg into per-lane MFMA B-fragment order, zero-padded to [KP][NP].
__global__ __launch_bounds__(256) void k_packb(const float* wn, const float* tg,
                                               unsigned short* bpack) {
  int t = blockIdx.x * 256 + threadIdx.x;
  int total = 2 * NT * KS * 64;
  if (t >= total) return;
  int m    = t / (NT * KS * 64);
  int rem  = t % (NT * KS * 64);
  int nt   = rem / (KS * 64);
  int rem2 = rem % (KS * 64);
  int ks   = rem2 / 64, lane = rem2 % 64;
  const float* W = m ? tg : wn;
  int n = nt * 16 + (lane & 15);
  unsigned short out[8];
  #pragma unroll
  for (int j = 0; j < 8; j++) {
    int k = ks * 32 + (lane >> 4) * 8 + j;
    float v = (k < H && n < H) ? W[k * H + n] : 0.f;
    out[j] = f2bu(v);
  }
  unsigned short* dst = bpack + (size_t)t * 8;
  #pragma unroll
  for (int j = 0; j < 8; j++) dst[j] = out[j];
}

// pack W_ih [600,400] and W_hh [600,200] (row-major [n][k]) into B-frag order
__global__ __launch_bounds__(256) void k_packgru(const float* __restrict__ wih,
                                                 const float* __restrict__ whh,
                                                 unsigned short* __restrict__ bgi,
                                                 unsigned short* __restrict__ bgh) {
  int t = blockIdx.x * 256 + threadIdx.x;
  const int tot_i = GNT * GKI * 64;
  const int tot_h = GNT * GKH * 64;
  if (t < tot_i) {
    int nt = t / (GKI * 64);
    int rem = t % (GKI * 64);
    int ks = rem / 64, lane = rem % 64;
    int n = nt * 16 + (lane & 15);
    unsigned short o[8];
    #pragma unroll
    for (int j = 0; j < 8; j++) {
      int k = ks * 32 + (lane >> 4) * 8 + j;
      o[j] = (n < 3 * H && k < 2 * H) ? f2bu(wih[n * (2 * H) + k]) : (unsigned short)0;
    }
    unsigned short* dstp = bgi + (size_t)t * 8;
    #pragma unroll
    for (int j = 0; j < 8; j++) dstp[j] = o[j];
  } else if (t < tot_i + tot_h) {
    int t2 = t - tot_i;
    int nt = t2 / (GKH * 64);
    int rem = t2 % (GKH * 64);
    int ks = rem / 64, lane = rem % 64;
    int n = nt * 16 + (lane & 15);
    unsigned short o[8];
    #pragma unroll
    for (int j = 0; j < 8; j++) {
      int k = ks * 32 + (lane >> 4) * 8 + j;
      o[j] = (n < 3 * H && k < H) ? f2bu(whh[n * H + k]) : (unsigned short)0;
    }
    unsigned short* dstp = bgh + (size_t)t2 * 8;
    #pragma unroll
    for (int j = 0; j < 8; j++) dstp[j] = o[j];
  }
}

// build GRU A-matrices: xcatb [512][416] = [emb_rel | seg-mean], h0b [512][224]
__global__ __launch_bounds__(256) void k_a2b(const float* __restrict__ er,
                                             const float* __restrict__ sums,
                                             const int* __restrict__ segstart,
                                             const float* __restrict__ h0,
                                             unsigned short* __restrict__ xcatb,
                                             unsigned short* __restrict__ h0b) {
  int i = blockIdx.x * 256 + threadIdx.x;
  const int n1 = GR * 416;
  if (i < n1) {
    int r = i / 416, c = i % 416;
    float v = 0.f;
    if (r < R2C) {
      if (c < H) v = er[r * H + c];
      else if (c < 2 * H) {
        int cnt = segstart[r + 1] - segstart[r];
        float inv = cnt > 0 ? 1.0f / (float)cnt : 0.0f;
        v = sums[r * H + (c - H)] * inv;
      }
    }
    xcatb[i] = f2bu(v);
  } else {
    int i2 = i - n1;
    if (i2 < GR * 224) {
      int r = i2 / 224, c = i2 % 224;
      float v = (r < R2C && c < H) ? h0[r * H + c] : 0.f;
      h0b[i2] = f2bu(v);
    }
  }
}

// ---------------- generic zero ----------------
__global__ void k_zero_f(float* p, int n) {
  int i = blockIdx.x * 256 + threadIdx.x;
  if (i < n) p[i] = 0.f;
}
__global__ void k_zero_i(int* p, int n) {
  int i = blockIdx.x * 256 + threadIdx.x;
  if (i < n) p[i] = 0;
}

// ---------------- prologue: relation segment bounds for ALL steps ----------------
__global__ __launch_bounds__(512) void k_segbounds4(const int* __restrict__ rseg,
                                                    int* __restrict__ segstart4) {
  const int* rs = rseg + (size_t)blockIdx.x * EC;
  int* out = segstart4 + blockIdx.x * (R2C + 1);
  for (int r = threadIdx.x; r <= R2C; r += 512) {
    int lo = 0, hi = EC;
    while (lo < hi) { int m = (lo + hi) >> 1; if (rs[m] < r) lo = m + 1; else hi = m; }
    out[r] = lo;
  }
}

// ---------------- prologue: CSR build for ALL steps (ILP-4) ----------------
__global__ void k_hist4(const int* __restrict__ dst, int* __restrict__ deg4) {
  int base = (blockIdx.x * 256 + threadIdx.x) * 4;
  if (base + 3 < TS * EC) {
    int4 d4 = *reinterpret_cast<const int4*>(dst + base);
    int t = base / EC;   // EC%4==0, base%4==0 -> whole quad in one step
    atomicAdd(&deg4[t * NE + d4.x], 1);
    atomicAdd(&deg4[t * NE + d4.y], 1);
    atomicAdd(&deg4[t * NE + d4.z], 1);
    atomicAdd(&deg4[t * NE + d4.w], 1);
  }
}

__global__ __launch_bounds__(256) void k_scan1(const int* __restrict__ deg4,
                                               int* __restrict__ offs4,
                                               int* __restrict__ bsums4) {
  __shared__ int s[256];
  int t = blockIdx.x / NSCAN, blk = blockIdx.x % NSCAN;
  int i = blk * 256 + threadIdx.x;
  int v = (i < NE) ? deg4[t * NE + i] : 0;
  s[threadIdx.x] = v;
  __syncthreads();
  for (int o = 1; o < 256; o <<= 1) {
    int add = (threadIdx.x >= o) ? s[threadIdx.x - o] : 0;
    __syncthreads();
    s[threadIdx.x] += add;
    __syncthreads();
  }
  if (i < NE) offs4[t * (NE + 1) + i] = s[threadIdx.x] - v;  // exclusive
  if (threadIdx.x == 255) bsums4[t * 256 + blk] = s[255];
}

__global__ __launch_bounds__(256) void k_scan2(int* bsums4) {
  __shared__ int s[256];
  int t = blockIdx.x;
  int v = (threadIdx.x < NSCAN) ? bsums4[t * 256 + threadIdx.x] : 0;
  s[threadIdx.x] = v;
  __syncthreads();
  for (int o = 1; o < 256; o <<= 1) {
    int add = (threadIdx.x >= o) ? s[threadIdx.x - o] : 0;
    __syncthreads();
    s[threadIdx.x] += add;
    __syncthreads();
  }
  if (threadIdx.x < NSCAN) bsums4[t * 256 + threadIdx.x] = s[threadIdx.x] - v;  // exclusive
}

__global__ void k_scan3(int* __restrict__ offs4, const int* __restrict__ bsums4,
                        int* __restrict__ cursor4) {
  int t = blockIdx.x / NSCAN, blk = blockIdx.x % NSCAN;
  int i = blk * 256 + threadIdx.x;
  if (i < NE) {
    int o = offs4[t * (NE + 1) + i] + bsums4[t * 256 + blk];
    offs4[t * (NE + 1) + i] = o;
    cursor4[t * NE + i] = o;
  }
  if (blk == 0 && threadIdx.x == 0) offs4[t * (NE + 1) + NE] = EC;
}

// dst-range-partitioned scatter: blockIdx&7 selects dst range so all writes to a
// given se/cursor line come from one XCD -> full-line writebacks.
__global__ void k_scatter8(const int* __restrict__ dst, const int* __restrict__ src,
                           const int* __restrict__ et, int* __restrict__ cursor4,
                           unsigned int* __restrict__ se4) {
  int r = blockIdx.x & (NRNG - 1);
  int rest = blockIdx.x >> 3;
  int t = rest % TS;
  int chunk = rest / TS;
  int li = chunk * SCHK + threadIdx.x * 4;
  if (li >= EC) return;                     // EC%4==0 so full quad when li<EC
  int base = t * EC + li;
  int4 d4 = *reinterpret_cast<const int4*>(dst + base);
  int4 s4 = *reinterpret_cast<const int4*>(src + base);
  int4 e4 = *reinterpret_cast<const int4*>(et + base);
  int* cur = cursor4 + t * NE;
  unsigned int* se = se4 + (size_t)t * EC;
  if ((unsigned)d4.x / DRNG == (unsigned)r) {
    int p = atomicAdd(&cur[d4.x], 1);
    se[p] = (unsigned int)s4.x | ((unsigned int)e4.x << 16);
  }
  if ((unsigned)d4.y / DRNG == (unsigned)r) {
    int p = atomicAdd(&cur[d4.y], 1);
    se[p] = (unsigned int)s4.y | ((unsigned int)e4.y << 16);
  }
  if ((unsigned)d4.z / DRNG == (unsigned)r) {
    int p = atomicAdd(&cur[d4.z], 1);
    se[p] = (unsigned int)s4.z | ((unsigned int)e4.z << 16);
  }
  if ((unsigned)d4.w / DRNG == (unsigned)r) {
    int p = atomicAdd(&cur[d4.w], 1);
    se[p] = (unsigned int)s4.w | ((unsigned int)e4.w << 16);
  }
}

// ---------------- per-step: segment-sum over sorted rseg (round-11 block structure) ----------------
// 64 edges/block, thread d owns dim d, ILP-8 groups, atomic flush on boundaries only.
__global__ __launch_bounds__(256) void k_relsums(const int* __restrict__ rseg,
                                                 const int* __restrict__ rte,
                                                 const unsigned short* __restrict__ hb,
                                                 float* __restrict__ sums) {
  int base = blockIdx.x * RCH;
  int d = threadIdx.x;
  bool act = d < H;
  float a0 = 0.f, a1 = 0.f, a2 = 0.f, a3 = 0.f;
  int prev = rseg[base];
  for (int g = 0; g < RCH; g += 8) {
    int e = base + g;
    int4 sgA = *reinterpret_cast<const int4*>(rseg + e);
    int4 sgB = *reinterpret_cast<const int4*>(rseg + e + 4);
    int4 rrA = *reinterpret_cast<const int4*>(rte + e);
    int4 rrB = *reinterpret_cast<const int4*>(rte + e + 4);
    if (sgB.w == prev) {           // sorted => whole group of 8 in same segment
      if (act) {
        float v0 = u2f(hb[(size_t)rrA.x * KP + d]);
        float v1 = u2f(hb[(size_t)rrA.y * KP + d]);
        float v2 = u2f(hb[(size_t)rrA.z * KP + d]);
        float v3 = u2f(hb[(size_t)rrA.w * KP + d]);
        float v4 = u2f(hb[(size_t)rrB.x * KP + d]);
        float v5 = u2f(hb[(size_t)rrB.y * KP + d]);
        float v6 = u2f(hb[(size_t)rrB.z * KP + d]);
        float v7 = u2f(hb[(size_t)rrB.w * KP + d]);
        a0 += v0; a1 += v1; a2 += v2; a3 += v3;
        a0 += v4; a1 += v5; a2 += v6; a3 += v7;
      }
    } else {                       // boundary group (rare): scalar path
      int ss[8] = {sgA.x, sgA.y, sgA.z, sgA.w, sgB.x, sgB.y, sgB.z, sgB.w};
      int rr[8] = {rrA.x, rrA.y, rrA.z, rrA.w, rrB.x, rrB.y, rrB.z, rrB.w};
      #pragma unroll
      for (int j = 0; j < 8; j++) {
        if (ss[j] != prev) {
          if (act) atomicAdd(&sums[prev * H + d], a0 + a1 + a2 + a3);
          a0 = a1 = a2 = a3 = 0.f;
          prev = ss[j];
        }
        if (act) a0 += u2f(hb[(size_t)rr[j] * KP + d]);
      }
    }
  }
  if (act) atomicAdd(&sums[prev * H + d], a0 + a1 + a2 + a3);
}

// ---------------- per-step: GRU GEMMs via MFMA -> gi, gh [512][608] f32 ----------------
__global__ __launch_bounds__(256) void k_grumm(const unsigned short* __restrict__ xcatb,
                                               const unsigned short* __restrict__ h0b,
                                               const unsigned short* __restrict__ bgi,
                                               const unsigned short* __restrict__ bgh,
                                               float* __restrict__ gi_ws,
                                               float* __restrict__ gh_ws) {
  int wid = threadIdx.x >> 6, lane = threadIdx.x & 63;
  int nt   = blockIdx.x % GNT;
  int row0 = (blockIdx.x / GNT) * 64 + wid * 16;
  int arow = row0 + (lane & 15);

  const unsigned short* api = xcatb + (size_t)arow * 416 + (lane >> 4) * 8;
  bf16x8v ai[GKI];
  #pragma unroll
  for (int ks = 0; ks < GKI; ks++)
    ai[ks] = *reinterpret_cast<const bf16x8v*>(api + ks * 32);
  const unsigned short* aph = h0b + (size_t)arow * 224 + (lane >> 4) * 8;
  bf16x8v ah[GKH];
  #pragma unroll
  for (int ks = 0; ks < GKH; ks++)
    ah[ks] = *reinterpret_cast<const bf16x8v*>(aph + ks * 32);

  const unsigned short* bip = bgi + ((size_t)(nt * GKI) * 64 + lane) * 8;
  bf16x8v bi[GKI];
  #pragma unroll
  for (int ks = 0; ks < GKI; ks++)
    bi[ks] = *reinterpret_cast<const bf16x8v*>(bip + (size_t)ks * 64 * 8);
  const unsigned short* bhp = bgh + ((size_t)(nt * GKH) * 64 + lane) * 8;
  bf16x8v bh[GKH];
  #pragma unroll
  for (int ks = 0; ks < GKH; ks++)
    bh[ks] = *reinterpret_cast<const bf16x8v*>(bhp + (size_t)ks * 64 * 8);

  f32x4 a1 = {}, a2 = {};
  #pragma unroll
  for (int ks = 0; ks < GKI; ks++)
    a1 = __builtin_amdgcn_mfma_f32_16x16x32_bf16(ai[ks], bi[ks], a1, 0, 0, 0);
  #pragma unroll
  for (int ks = 0; ks < GKH; ks++)
    a2 = __builtin_amdgcn_mfma_f32_16x16x32_bf16(ah[ks], bh[ks], a2, 0, 0, 0);

  int col = nt * 16 + (lane & 15);
  int rb = row0 + (lane >> 4) * 4;
  #pragma unroll
  for (int q = 0; q < 4; q++) {
    gi_ws[(size_t)(rb + q) * GCS + col] = a1[q];
    gh_ws[(size_t)(rb + q) * GCS + col] = a2[q];
  }
}

// ---------------- per-step: GRU gates + l2norm -> h0 (and h0_out on last step) ----------------
__global__ __launch_bounds__(256) void k_grutail(const float* __restrict__ gi_ws,
                                                 const float* __restrict__ gh_ws,
                                                 const float* __restrict__ b_ih,
                                                 const float* __restrict__ b_hh,
                                                 float* __restrict__ h0,
                                                 float* __restrict__ h0_out) {
  __shared__ float xc[H];
  __shared__ float red[4];
  int r = blockIdx.x;
  int tid = threadIdx.x, wid = tid >> 6, lane = tid & 63;
  float ssp = 0.f;
  for (int d = tid; d < H; d += 256) {
    float gir = gi_ws[(size_t)r * GCS + d]         + b_ih[d];
    float ghr = gh_ws[(size_t)r * GCS + d]         + b_hh[d];
    float giz = gi_ws[(size_t)r * GCS + H + d]     + b_ih[H + d];
    float ghz = gh_ws[(size_t)r * GCS + H + d]     + b_hh[H + d];
    float gin = gi_ws[(size_t)r * GCS + 2 * H + d] + b_ih[2 * H + d];
    float ghn = gh_ws[(size_t)r * GCS + 2 * H + d] + b_hh[2 * H + d];
    float rg = sigmoidf(gir + ghr);
    float z  = sigmoidf(giz + ghz);
    float n  = tanhf(gin + rg * ghn);
    float hv = h0[r * H + d];
    float o  = (1.0f - z) * n + z * hv;
    xc[d] = o;
    ssp += o * o;
  }
  ssp = wave_sum(ssp);
  if (lane == 0) red[wid] = ssp;
  __syncthreads();
  float ss = red[0] + red[1] + red[2] + red[3];
  float sc = 1.0f / fmaxf(sqrtf(ss), 1e-12f);
  for (int d = tid; d < H; d += 256) {
    float o = xc[d] * sc;
    h0[r * H + d] = o;
    if (h0_out) h0_out[r * H + d] = o;
  }
}

// ---------------- per-step: MFMA node GEMMs (hW = h@Wn, tw = sigmoid(h@Tg+b)) ----------------
__global__ __launch_bounds__(256) void k_mfma_gemm(const unsigned short* __restrict__ hb,
                                                   const unsigned short* __restrict__ bpack,
                                                   const float* __restrict__ tgb,
                                                   bf16* __restrict__ hWb,
                                                   bf16* __restrict__ twb) {
  int wid = threadIdx.x >> 6, lane = threadIdx.x & 63;
  int row0 = blockIdx.x * 64 + wid * 16;
  if (row0 >= NE) return;                 // wave-uniform
  int arow = min(row0 + (lane & 15), NE - 1);
  const unsigned short* ap = hb + (size_t)arow * KP + (lane >> 4) * 8;
  bf16x8v a[KS];
  #pragma unroll
  for (int ks = 0; ks < KS; ks++)
    a[ks] = *reinterpret_cast<const bf16x8v*>(ap + ks * 32);

  const unsigned short* b1p = bpack + (size_t)lane * 8;
  const unsigned short* b2p = b1p + (size_t)NT * KS * 64 * 8;
  int colb = lane & 15;
  int rbase = row0 + (lane >> 4) * 4;

  for (int nt = 0; nt < NT; nt++) {
    bf16x8v b1[KS], b2[KS];
    #pragma unroll
    for (int ks = 0; ks < KS; ks++) {
      size_t boff = (size_t)(nt * KS + ks) * 64 * 8;
      b1[ks] = *reinterpret_cast<const bf16x8v*>(b1p + boff);
      b2[ks] = *reinterpret_cast<const bf16x8v*>(b2p + boff);
    }
    f32x4 acc1 = {}, acc2 = {};
    #pragma unroll
    for (int ks = 0; ks < KS; ks++) {
      acc1 = __builtin_amdgcn_mfma_f32_16x16x32_bf16(a[ks], b1[ks], acc1, 0, 0, 0);
      acc2 = __builtin_amdgcn_mfma_f32_16x16x32_bf16(a[ks], b2[ks], acc2, 0, 0, 0);
    }
    int col = nt * 16 + colb;
    bool cok = (col < H);
    float bias = cok ? tgb[col] : 0.f;
    #pragma unroll
    for (int q = 0; q < 4; q++) {
      int row = rbase + q;
      if (cok && row < NE) {
        hWb[(size_t)row * H + col] = f2b(acc1[q]);
        twb[(size_t)row * H + col] = f2b(sigmoidf(acc2[q] + bias));
      }
    }
  }
}

// ---------------- per-step: aggregate + rrelu + l2norm + time gate + l2norm ----------------
// fused; also emits next step's bf16 hb (padded) when hbnext != null.
__global__ __launch_bounds__(256) void k_aggfin(const int* __restrict__ offs,
                                                const unsigned int* __restrict__ se,
                                                const bf16* __restrict__ hWb,
                                                const unsigned short* __restrict__ relWb,
                                                const bf16* __restrict__ twb,
                                                float* __restrict__ h,
                                                float* __restrict__ evolve,
                                                unsigned short* __restrict__ hbnext) {
  int wid = threadIdx.x >> 6, lane = threadIdx.x & 63;
  int i = blockIdx.x * 4 + wid;
  if (i >= NE) return;
  int s0 = offs[i], s1 = offs[i + 1];
  int d0 = lane * 4;
  bool act = d0 < H;
  const unsigned short* hw = (const unsigned short*)hWb;
  float a0 = 0.f, a1 = 0.f, a2 = 0.f, a3 = 0.f;

  int p = s0;
  for (; p + 4 <= s1; p += 4) {
    unsigned int e0 = se[p], e1 = se[p + 1], e2 = se[p + 2], e3 = se[p + 3];
    if (act) {
      ushort4 m0 = *reinterpret_cast<const ushort4*>(hw + (size_t)(e0 & 0xFFFFu) * H + d0);
      ushort4 m1 = *reinterpret_cast<const ushort4*>(hw + (size_t)(e1 & 0xFFFFu) * H + d0);
      ushort4 m2 = *reinterpret_cast<const ushort4*>(hw + (size_t)(e2 & 0xFFFFu) * H + d0);
      ushort4 m3 = *reinterpret_cast<const ushort4*>(hw + (size_t)(e3 & 0xFFFFu) * H + d0);
      ushort4 r0 = *reinterpret_cast<const ushort4*>(relWb + (size_t)(e0 >> 16) * H + d0);
      ushort4 r1 = *reinterpret_cast<const ushort4*>(relWb + (size_t)(e1 >> 16) * H + d0);
      ushort4 r2 = *reinterpret_cast<const ushort4*>(relWb + (size_t)(e2 >> 16) * H + d0);
      ushort4 r3 = *reinterpret_cast<const ushort4*>(relWb + (size_t)(e3 >> 16) * H + d0);
      a0 += u2f(m0.x) + u2f(r0.x) + u2f(m1.x) + u2f(r1.x)
          + u2f(m2.x) + u2f(r2.x) + u2f(m3.x) + u2f(r3.x);
      a1 += u2f(m0.y) + u2f(r0.y) + u2f(m1.y) + u2f(r1.y)
          + u2f(m2.y) + u2f(r2.y) + u2f(m3.y) + u2f(r3.y);
      a2 += u2f(m0.z) + u2f(r0.z) + u2f(m1.z) + u2f(r1.z)
          + u2f(m2.z) + u2f(r2.z) + u2f(m3.z) + u2f(r3.z);
      a3 += u2f(m0.w) + u2f(r0.w) + u2f(m1.w) + u2f(r1.w)
          + u2f(m2.w) + u2f(r2.w) + u2f(m3.w) + u2f(r3.w);
    }
  }
  for (; p < s1; p++) {
    unsigned int e0 = se[p];
    if (act) {
      ushort4 m0 = *reinterpret_cast<const ushort4*>(hw + (size_t)(e0 & 0xFFFFu) * H + d0);
      ushort4 r0 = *reinterpret_cast<const ushort4*>(relWb + (size_t)(e0 >> 16) * H + d0);
      a0 += u2f(m0.x) + u2f(r0.x);
      a1 += u2f(m0.y) + u2f(r0.y);
      a2 += u2f(m0.z) + u2f(r0.z);
      a3 += u2f(m0.w) + u2f(r0.w);
    }
  }

  int deg = s1 - s0;
  float nrm = deg > 0 ? 1.0f / (float)deg : 0.0f;
  float c0 = a0 * nrm; c0 = c0 >= 0.f ? c0 : SLOPE * c0;
  float c1 = a1 * nrm; c1 = c1 >= 0.f ? c1 : SLOPE * c1;
  float c2 = a2 * nrm; c2 = c2 >= 0.f ? c2 : SLOPE * c2;
  float c3 = a3 * nrm; c3 = c3 >= 0.f ? c3 : SLOPE * c3;
  float ss = act ? (c0 * c0 + c1 * c1 + c2 * c2 + c3 * c3) : 0.f;
  ss = wave_sum(ss);
  float sc = 1.0f / fmaxf(sqrtf(ss), 1e-12f);
  c0 *= sc; c1 *= sc; c2 *= sc; c3 *= sc;

  // time gate + combine + l2norm
  float v0 = 0.f, v1 = 0.f, v2 = 0.f, v3 = 0.f;
  if (act) {
    ushort4 t4 = *reinterpret_cast<const ushort4*>((const unsigned short*)twb + (size_t)i * H + d0);
    float4 hv = *reinterpret_cast<const float4*>(h + (size_t)i * H + d0);
    float t0 = u2f(t4.x), t1 = u2f(t4.y), t2 = u2f(t4.z), t3 = u2f(t4.w);
    v0 = t0 * c0 + (1.0f - t0) * hv.x;
    v1 = t1 * c1 + (1.0f - t1) * hv.y;
    v2 = t2 * c2 + (1.0f - t2) * hv.z;
    v3 = t3 * c3 + (1.0f - t3) * hv.w;
  }
  float ss2 = v0 * v0 + v1 * v1 + v2 * v2 + v3 * v3;
  ss2 = wave_sum(ss2);
  float sc2 = 1.0f / fmaxf(sqrtf(ss2), 1e-12f);
  if (act) {
    float4 o = make_float4(v0 * sc2, v1 * sc2, v2 * sc2, v3 * sc2);
    *reinterpret_cast<float4*>(h + (size_t)i * H + d0) = o;
    *reinterpret_cast<float4*>(evolve + (size_t)i * H + d0) = o;
    if (hbnext) {
      ushort4 ob; ob.x = f2bu(o.x); ob.y = f2bu(o.y); ob.z = f2bu(o.z); ob.w = f2bu(o.w);
      *reinterpret_cast<ushort4*>(hbnext + (size_t)i * KP + d0) = ob;
    }
  } else if (d0 < KP && hbnext) {
    ushort4 z; z.x = z.y = z.z = z.w = 0;
    *reinterpret_cast<ushort4*>(hbnext + (size_t)i * KP + d0) = z;
  }
}

extern "C" void kernel_launch(void* const* d_in, const int* in_sizes, int n_in,
                              void* d_out, int out_size, void* d_ws, size_t ws_size,
                              hipStream_t stream) {
  const float* de  = (const float*)d_in[0];
  const float* er  = (const float*)d_in[1];
  const float* wih = (const float*)d_in[2];
  const float* whh = (const float*)d_in[3];
  const float* bih = (const float*)d_in[4];
  const float* bhh = (const float*)d_in[5];
  const float* wn  = (const float*)d_in[6];
  const float* tg  = (const float*)d_in[7];
  const float* tgb = (const float*)d_in[8];
  const int* src  = (const int*)d_in[9];
  const int* dst  = (const int*)d_in[10];
  const int* et   = (const int*)d_in[11];
  const int* rte  = (const int*)d_in[12];
  const int* rseg = (const int*)d_in[13];

  char* w = (char*)d_ws;
  auto alloc = [&](size_t bytes) -> char* {
    char* p = w;
    w += (bytes + 255) / 256 * 256;
    return p;
  };
  float* h     = (float*)alloc(sizeof(float) * (size_t)NE * H);   // 40 MB
  bf16*  hWb   = (bf16*) alloc(sizeof(bf16)  * (size_t)NE * H);   // 20 MB
  bf16*  twb   = (bf16*) alloc(sizeof(bf16)  * (size_t)NE * H);   // 20 MB
  unsigned short* relWb = (unsigned short*)alloc(sizeof(unsigned short) * R2C * H); // 200 KB
  float* h0    = (float*)alloc(sizeof(float) * R2C * H);
  float* sums4 = (float*)alloc(sizeof(float) * TS * R2C * H);     // 1.6 MB
  unsigned short* bpack = (unsigned short*)alloc(sizeof(unsigned short) * 2 * NT * KS * 64 * 8); // 186 KB
  unsigned short* bgi   = (unsigned short*)alloc(sizeof(unsigned short) * GNT * GKI * 64 * 8);   // 506 KB
  unsigned short* bgh   = (unsigned short*)alloc(sizeof(unsigned short) * GNT * GKH * 64 * 8);   // 272 KB
  unsigned short* xcatb = (unsigned short*)alloc(sizeof(unsigned short) * GR * 416);             // 416 KB
  unsigned short* h0b   = (unsigned short*)alloc(sizeof(unsigned short) * GR * 224);             // 224 KB
  float* gi_ws = (float*)alloc(sizeof(float) * GR * GCS);          // 1.24 MB
  float* gh_ws = (float*)alloc(sizeof(float) * GR * GCS);          // 1.24 MB
  int* segstart4 = (int*)alloc(sizeof(int) * TS * (R2C + 1));
  int* deg4    = (int*) alloc(sizeof(int) * TS * NE);              // 800 KB
  int* offs4   = (int*) alloc(sizeof(int) * TS * (NE + 1));        // 800 KB
  int* cursor4 = (int*) alloc(sizeof(int) * TS * NE);              // 800 KB
  unsigned int* se4 = (unsigned int*)alloc(sizeof(unsigned int) * (size_t)TS * EC); // 6.4 MB
  int* bsums4  = (int*) alloc(sizeof(int) * TS * 256);
  (void)ws_size; (void)in_sizes; (void)n_in; (void)out_size;

  float* out    = (float*)d_out;
  float* evolve = out;                       // [TS, NE, H]
  float* h0out  = out + (size_t)TS * NE * H; // [R2C, H]

  const int gRow4  = (NE + 3) / 4;          // 12500
  const int gRel   = (R2C * H + 255) / 256; // 391
  const int gPack  = (2 * NT * KS * 64 + 255) / 256;       // 46
  const int gPackG = (GNT * (GKI + GKH) * 64 + 255) / 256; // 190
  const int gA2b   = (GR * 416 + GR * 224 + 255) / 256;    // 1280
  const int gGemm  = (NE + 63) / 64;                       // 782
  const int gGru   = 8 * GNT;                              // 304
  const int gRelsum= EC / RCH;                             // 6250
  const int gE4i   = (TS * EC / 4 + 255) / 256;            // 1563
  const int gZ4    = (TS * NE + 255) / 256;                // 782
  const int gZs    = (TS * R2C * H + 255) / 256;           // 1563
  const int gScat  = NCHK * TS * NRNG;                     // 12512

  // ---- prologue: init + weight packs + all-step CSR / segment bounds ----
  k_init_h<<<gRow4, 256, 0, stream>>>(de, h, (unsigned short*)evolve);  // hb0 in evolve[0] slot
  k_init_h0<<<gRel, 256, 0, stream>>>(er, h0);
  k_relw<<<R2C, 256, 0, stream>>>(er, wn, relWb);
  k_packb<<<gPack, 256, 0, stream>>>(wn, tg, bpack);
  k_packgru<<<gPackG, 256, 0, stream>>>(wih, whh, bgi, bgh);
  k_segbounds4<<<TS, 512, 0, stream>>>(rseg, segstart4);
  k_zero_f<<<gZs, 256, 0, stream>>>(sums4, TS * R2C * H);
  k_zero_i<<<gZ4, 256, 0, stream>>>(deg4, TS * NE);
  k_hist4<<<gE4i, 256, 0, stream>>>(dst, deg4);
  k_scan1<<<TS * NSCAN, 256, 0, stream>>>(deg4, offs4, bsums4);
  k_scan2<<<TS, 256, 0, stream>>>(bsums4);
  k_scan3<<<TS * NSCAN, 256, 0, stream>>>(offs4, bsums4, cursor4);
  k_scatter8<<<gScat, 256, 0, stream>>>(dst, src, et, cursor4, se4);

  for (int t = 0; t < TS; t++) {
    const int* rseg_t = rseg + (size_t)t * EC;
    const int* rte_t  = rte  + (size_t)t * EC;
    float* sums_t = sums4 + (size_t)t * R2C * H;
    float* evo_t = evolve + (size_t)t * NE * H;
    // hb(t) lives in the evolve[t] slot (written by k_init_h for t=0, else by
    // the previous step's k_aggfin); it is dead before k_aggfin overwrites it.
    unsigned short* hb = (unsigned short*)evo_t;
    unsigned short* hbnext = (t < TS - 1) ? (unsigned short*)(evolve + (size_t)(t + 1) * NE * H)
                                          : (unsigned short*)nullptr;

    // relation-segment means + GRU via MFMA (uses pre-step h, h0)
    k_relsums<<<gRelsum, 256, 0, stream>>>(rseg_t, rte_t, hb, sums_t);
    k_a2b<<<gA2b, 256, 0, stream>>>(er, sums_t, segstart4 + t * (R2C + 1), h0, xcatb, h0b);
    k_grumm<<<gGru, 256, 0, stream>>>(xcatb, h0b, bgi, bgh, gi_ws, gh_ws);
    k_grutail<<<R2C, 256, 0, stream>>>(gi_ws, gh_ws, bih, bhh,
                                       h0, (t == TS - 1) ? h0out : (float*)nullptr);

    // node GEMMs via MFMA (pre-step h)
    k_mfma_gemm<<<gGemm, 256, 0, stream>>>(hb, bpack, tgb, hWb, twb);

    // fused aggregate + rrelu + l2norm + time gate + combine + l2norm
    // -> writes h (in place), evolve[t], and next step's hb
    k_aggfin<<<gRow4, 256, 0, stream>>>(offs4 + t * (NE + 1), se4 + (size_t)t * EC,
                                        hWb, relWb, twb, h, evo_t, hbnext);
  }
}

// Round 16
// 695.406 us; speedup vs baseline: 1.0613x; 1.0613x over previous
//
#include <hip/hip_runtime.h>
#include <hip/hip_bf16.h>

using bf16 = __hip_bfloat16;

constexpr int NE  = 50000;   // entities
constexpr int H   = 200;     // hidden dim
constexpr int R2C = 500;     // 2*num_rels
constexpr int TS  = 4;       // timesteps
constexpr int EC  = 400000;  // edges per step
constexpr float SLOPE = 0.22916666666666666f;  // rrelu eval slope
constexpr int NSCAN = (NE + 255) / 256;        // 196

// node-GEMM MFMA geometry
constexpr int KP = 224;      // K padded to 7*32
constexpr int KS = 7;        // k-steps of 32
constexpr int NT = 13;       // n-tiles of 16

// GRU-GEMM MFMA geometry (out [512][608])
constexpr int GNT = 38;      // n-tiles (608/16)
constexpr int GKI = 13;      // k-steps for W_ih (416/32)
constexpr int GKH = 7;       // k-steps for W_hh (224/32)
constexpr int GR  = 512;     // padded relation rows
constexpr int GCS = 608;     // padded gate cols (stride)

constexpr int RCH = 64;      // edges per block in relsums part
constexpr int NRNG = 8;      // dst ranges (≈ XCD count); NE/NRNG = 6250
constexpr int DRNG = NE / NRNG;              // 6250
constexpr int SCHK = 1024;   // edges per scatter chunk
constexpr int NCHK = (EC + SCHK - 1) / SCHK; // 391

// fused-kernel block counts
constexpr int GB_GEMM  = (NE + 63) / 64;     // 782
constexpr int GB_RELS  = EC / RCH;           // 6250
constexpr int GB_AGG   = (NE + 3) / 4;       // 12500
constexpr int GB_A2B   = (GR * 416 + GR * 224 + 255) / 256; // 1280

#define DEVINL __device__ __forceinline__

typedef __bf16 bf16x8v __attribute__((ext_vector_type(8)));
typedef float  f32x4   __attribute__((ext_vector_type(4)));

DEVINL float b2f(bf16 v) { return __bfloat162float(v); }
DEVINL bf16  f2b(float v) { return __float2bfloat16(v); }
DEVINL unsigned short f2bu(float x) { bf16 b = f2b(x); return *reinterpret_cast<unsigned short*>(&b); }
DEVINL float u2f(unsigned short u) { unsigned int w = (unsigned int)u << 16; float f; __builtin_memcpy(&f, &w, 4); return f; }

DEVINL float wave_sum(float v) {
  #pragma unroll
  for (int o = 32; o > 0; o >>= 1) v += __shfl_xor(v, o, 64);
  return v;
}

DEVINL float sigmoidf(float x) { return 1.0f / (1.0f + expf(-x)); }

// ---------------- init: l2norm rows of dynamic_emb -> h (f32) AND hb0 (bf16 padded) ----------------
__global__ __launch_bounds__(256) void k_init_h(const float* __restrict__ de,
                                                float* __restrict__ h,
                                                unsigned short* __restrict__ hb0) {
  int wid = threadIdx.x >> 6, lane = threadIdx.x & 63;
  int row = blockIdx.x * 4 + wid;
  if (row >= NE) return;
  int d0 = lane * 4;
  bool act = d0 < H;
  float4 v = make_float4(0.f, 0.f, 0.f, 0.f);
  if (act) v = *reinterpret_cast<const float4*>(de + (size_t)row * H + d0);
  float ss = v.x * v.x + v.y * v.y + v.z * v.z + v.w * v.w;
  ss = wave_sum(ss);
  float sc = 1.0f / fmaxf(sqrtf(ss), 1e-12f);
  if (act) {
    float4 o = make_float4(v.x * sc, v.y * sc, v.z * sc, v.w * sc);
    *reinterpret_cast<float4*>(h + (size_t)row * H + d0) = o;
    ushort4 ob; ob.x = f2bu(o.x); ob.y = f2bu(o.y); ob.z = f2bu(o.z); ob.w = f2bu(o.w);
    *reinterpret_cast<ushort4*>(hb0 + (size_t)row * KP + d0) = ob;
  } else if (d0 < KP) {
    ushort4 z; z.x = z.y = z.z = z.w = 0;
    *reinterpret_cast<ushort4*>(hb0 + (size_t)row * KP + d0) = z;
  }
}

__global__ __launch_bounds__(256) void k_init_h0(const float* er, float* h0) {
  int i = blockIdx.x * 256 + threadIdx.x;
  if (i < R2C * H) h0[i] = er[i];
}

// relWb = bf16(emb_rel @ W_n)   [R2C, H]
__global__ __launch_bounds__(256) void k_relw(const float* er, const float* wn,
                                              unsigned short* relWb) {
  __shared__ float a[H];
  int r = blockIdx.x;
  for (int d = threadIdx.x; d < H; d += 256) a[d] = er[r * H + d];
  __syncthreads();
  for (int c = threadIdx.x; c < H; c += 256) {
    float s = 0.f;
    for (int k = 0; k < H; k++) s += a[k] * wn[k * H + c];
    relWb[r * H + c] = f2bu(s);
  }
}

// pack Wn and Tg into per-lane MFMA B-fragment order, zero-padded to [KP][NP].
__global__ __launch_bounds__(256) void k_packb(const float* wn, const float* tg,
                                               unsigned short* bpack) {
  int t = blockIdx.x * 256 + threadIdx.x;
  int total = 2 * NT * KS * 64;
  if (t >= total) return;
  int m    = t / (NT * KS * 64);
  int rem  = t % (NT * KS * 64);
  int nt   = rem / (KS * 64);
  int rem2 = rem % (KS * 64);
  int ks   = rem2 / 64, lane = rem2 % 64;
  const float* W = m ? tg : wn;
  int n = nt * 16 + (lane & 15);
  unsigned short out[8];
  #pragma unroll
  for (int j = 0; j < 8; j++) {
    int k = ks * 32 + (lane >> 4) * 8 + j;
    float v = (k < H && n < H) ? W[k * H + n] : 0.f;
    out[j] = f2bu(v);
  }
  unsigned short* dst = bpack + (size_t)t * 8;
  #pragma unroll
  for (int j = 0; j < 8; j++) dst[j] = out[j];
}

// pack W_ih [600,400] and W_hh [600,200] (row-major [n][k]) into B-frag order
__global__ __launch_bounds__(256) void k_packgru(const float* __restrict__ wih,
                                                 const float* __restrict__ whh,
                                                 unsigned short* __restrict__ bgi,
                                                 unsigned short* __restrict__ bgh) {
  int t = blockIdx.x * 256 + threadIdx.x;
  const int tot_i = GNT * GKI * 64;
  const int tot_h = GNT * GKH * 64;
  if (t < tot_i) {
    int nt = t / (GKI * 64);
    int rem = t % (GKI * 64);
    int ks = rem / 64, lane = rem % 64;
    int n = nt * 16 + (lane & 15);
    unsigned short o[8];
    #pragma unroll
    for (int j = 0; j < 8; j++) {
      int k = ks * 32 + (lane >> 4) * 8 + j;
      o[j] = (n < 3 * H && k < 2 * H) ? f2bu(wih[n * (2 * H) + k]) : (unsigned short)0;
    }
    unsigned short* dstp = bgi + (size_t)t * 8;
    #pragma unroll
    for (int j = 0; j < 8; j++) dstp[j] = o[j];
  } else if (t < tot_i + tot_h) {
    int t2 = t - tot_i;
    int nt = t2 / (GKH * 64);
    int rem = t2 % (GKH * 64);
    int ks = rem / 64, lane = rem % 64;
    int n = nt * 16 + (lane & 15);
    unsigned short o[8];
    #pragma unroll
    for (int j = 0; j < 8; j++) {
      int k = ks * 32 + (lane >> 4) * 8 + j;
      o[j] = (n < 3 * H && k < H) ? f2bu(whh[n * H + k]) : (unsigned short)0;
    }
    unsigned short* dstp = bgh + (size_t)t2 * 8;
    #pragma unroll
    for (int j = 0; j < 8; j++) dstp[j] = o[j];
  }
}

// ---------------- generic zero ----------------
__global__ void k_zero_f(float* p, int n) {
  int i = blockIdx.x * 256 + threadIdx.x;
  if (i < n) p[i] = 0.f;
}
__global__ void k_zero_i(int* p, int n) {
  int i = blockIdx.x * 256 + threadIdx.x;
  if (i < n) p[i] = 0;
}

// ---------------- prologue: relation segment bounds for ALL steps ----------------
__global__ __launch_bounds__(512) void k_segbounds4(const int* __restrict__ rseg,
                                                    int* __restrict__ segstart4) {
  const int* rs = rseg + (size_t)blockIdx.x * EC;
  int* out = segstart4 + blockIdx.x * (R2C + 1);
  for (int r = threadIdx.x; r <= R2C; r += 512) {
    int lo = 0, hi = EC;
    while (lo < hi) { int m = (lo + hi) >> 1; if (rs[m] < r) lo = m + 1; else hi = m; }
    out[r] = lo;
  }
}

// ---------------- prologue: CSR build for ALL steps (ILP-4) ----------------
__global__ void k_hist4(const int* __restrict__ dst, int* __restrict__ deg4) {
  int base = (blockIdx.x * 256 + threadIdx.x) * 4;
  if (base + 3 < TS * EC) {
    int4 d4 = *reinterpret_cast<const int4*>(dst + base);
    int t = base / EC;   // EC%4==0, base%4==0 -> whole quad in one step
    atomicAdd(&deg4[t * NE + d4.x], 1);
    atomicAdd(&deg4[t * NE + d4.y], 1);
    atomicAdd(&deg4[t * NE + d4.z], 1);
    atomicAdd(&deg4[t * NE + d4.w], 1);
  }
}

__global__ __launch_bounds__(256) void k_scan1(const int* __restrict__ deg4,
                                               int* __restrict__ offs4,
                                               int* __restrict__ bsums4) {
  __shared__ int s[256];
  int t = blockIdx.x / NSCAN, blk = blockIdx.x % NSCAN;
  int i = blk * 256 + threadIdx.x;
  int v = (i < NE) ? deg4[t * NE + i] : 0;
  s[threadIdx.x] = v;
  __syncthreads();
  for (int o = 1; o < 256; o <<= 1) {
    int add = (threadIdx.x >= o) ? s[threadIdx.x - o] : 0;
    __syncthreads();
    s[threadIdx.x] += add;
    __syncthreads();
  }
  if (i < NE) offs4[t * (NE + 1) + i] = s[threadIdx.x] - v;  // exclusive
  if (threadIdx.x == 255) bsums4[t * 256 + blk] = s[255];
}

__global__ __launch_bounds__(256) void k_scan2(int* bsums4) {
  __shared__ int s[256];
  int t = blockIdx.x;
  int v = (threadIdx.x < NSCAN) ? bsums4[t * 256 + threadIdx.x] : 0;
  s[threadIdx.x] = v;
  __syncthreads();
  for (int o = 1; o < 256; o <<= 1) {
    int add = (threadIdx.x >= o) ? s[threadIdx.x - o] : 0;
    __syncthreads();
    s[threadIdx.x] += add;
    __syncthreads();
  }
  if (threadIdx.x < NSCAN) bsums4[t * 256 + threadIdx.x] = s[threadIdx.x] - v;  // exclusive
}

__global__ void k_scan3(int* __restrict__ offs4, const int* __restrict__ bsums4,
                        int* __restrict__ cursor4) {
  int t = blockIdx.x / NSCAN, blk = blockIdx.x % NSCAN;
  int i = blk * 256 + threadIdx.x;
  if (i < NE) {
    int o = offs4[t * (NE + 1) + i] + bsums4[t * 256 + blk];
    offs4[t * (NE + 1) + i] = o;
    cursor4[t * NE + i] = o;
  }
  if (blk == 0 && threadIdx.x == 0) offs4[t * (NE + 1) + NE] = EC;
}

// dst-range-partitioned scatter: blockIdx&7 selects dst range so all writes to a
// given se/cursor line come from one XCD -> full-line writebacks.
__global__ void k_scatter8(const int* __restrict__ dst, const int* __restrict__ src,
                           const int* __restrict__ et, int* __restrict__ cursor4,
                           unsigned int* __restrict__ se4) {
  int r = blockIdx.x & (NRNG - 1);
  int rest = blockIdx.x >> 3;
  int t = rest % TS;
  int chunk = rest / TS;
  int li = chunk * SCHK + threadIdx.x * 4;
  if (li >= EC) return;                     // EC%4==0 so full quad when li<EC
  int base = t * EC + li;
  int4 d4 = *reinterpret_cast<const int4*>(dst + base);
  int4 s4 = *reinterpret_cast<const int4*>(src + base);
  int4 e4 = *reinterpret_cast<const int4*>(et + base);
  int* cur = cursor4 + t * NE;
  unsigned int* se = se4 + (size_t)t * EC;
  if ((unsigned)d4.x / DRNG == (unsigned)r) {
    int p = atomicAdd(&cur[d4.x], 1);
    se[p] = (unsigned int)s4.x | ((unsigned int)e4.x << 16);
  }
  if ((unsigned)d4.y / DRNG == (unsigned)r) {
    int p = atomicAdd(&cur[d4.y], 1);
    se[p] = (unsigned int)s4.y | ((unsigned int)e4.y << 16);
  }
  if ((unsigned)d4.z / DRNG == (unsigned)r) {
    int p = atomicAdd(&cur[d4.z], 1);
    se[p] = (unsigned int)s4.z | ((unsigned int)e4.z << 16);
  }
  if ((unsigned)d4.w / DRNG == (unsigned)r) {
    int p = atomicAdd(&cur[d4.w], 1);
    se[p] = (unsigned int)s4.w | ((unsigned int)e4.w << 16);
  }
}

// ---------------- device bodies for fused kernels ----------------

// segment-sum over sorted rseg (round-11 block structure), block id = b
DEVINL void relsums_body(int b, const int* __restrict__ rseg, const int* __restrict__ rte,
                         const unsigned short* __restrict__ hb, float* __restrict__ sums) {
  int base = b * RCH;
  int d = threadIdx.x;
  bool act = d < H;
  float a0 = 0.f, a1 = 0.f, a2 = 0.f, a3 = 0.f;
  int prev = rseg[base];
  for (int g = 0; g < RCH; g += 8) {
    int e = base + g;
    int4 sgA = *reinterpret_cast<const int4*>(rseg + e);
    int4 sgB = *reinterpret_cast<const int4*>(rseg + e + 4);
    int4 rrA = *reinterpret_cast<const int4*>(rte + e);
    int4 rrB = *reinterpret_cast<const int4*>(rte + e + 4);
    if (sgB.w == prev) {           // sorted => whole group of 8 in same segment
      if (act) {
        float v0 = u2f(hb[(size_t)rrA.x * KP + d]);
        float v1 = u2f(hb[(size_t)rrA.y * KP + d]);
        float v2 = u2f(hb[(size_t)rrA.z * KP + d]);
        float v3 = u2f(hb[(size_t)rrA.w * KP + d]);
        float v4 = u2f(hb[(size_t)rrB.x * KP + d]);
        float v5 = u2f(hb[(size_t)rrB.y * KP + d]);
        float v6 = u2f(hb[(size_t)rrB.z * KP + d]);
        float v7 = u2f(hb[(size_t)rrB.w * KP + d]);
        a0 += v0; a1 += v1; a2 += v2; a3 += v3;
        a0 += v4; a1 += v5; a2 += v6; a3 += v7;
      }
    } else {                       // boundary group (rare): scalar path
      int ss[8] = {sgA.x, sgA.y, sgA.z, sgA.w, sgB.x, sgB.y, sgB.z, sgB.w};
      int rr[8] = {rrA.x, rrA.y, rrA.z, rrA.w, rrB.x, rrB.y, rrB.z, rrB.w};
      #pragma unroll
      for (int j = 0; j < 8; j++) {
        if (ss[j] != prev) {
          if (act) atomicAdd(&sums[prev * H + d], a0 + a1 + a2 + a3);
          a0 = a1 = a2 = a3 = 0.f;
          prev = ss[j];
        }
        if (act) a0 += u2f(hb[(size_t)rr[j] * KP + d]);
      }
    }
  }
  if (act) atomicAdd(&sums[prev * H + d], a0 + a1 + a2 + a3);
}

// node GEMMs via MFMA, block id = b
DEVINL void gemm_body(int b, const unsigned short* __restrict__ hb,
                      const unsigned short* __restrict__ bpack,
                      const float* __restrict__ tgb,
                      bf16* __restrict__ hWb, bf16* __restrict__ twb) {
  int wid = threadIdx.x >> 6, lane = threadIdx.x & 63;
  int row0 = b * 64 + wid * 16;
  if (row0 >= NE) return;                 // wave-uniform
  int arow = min(row0 + (lane & 15), NE - 1);
  const unsigned short* ap = hb + (size_t)arow * KP + (lane >> 4) * 8;
  bf16x8v a[KS];
  #pragma unroll
  for (int ks = 0; ks < KS; ks++)
    a[ks] = *reinterpret_cast<const bf16x8v*>(ap + ks * 32);

  const unsigned short* b1p = bpack + (size_t)lane * 8;
  const unsigned short* b2p = b1p + (size_t)NT * KS * 64 * 8;
  int colb = lane & 15;
  int rbase = row0 + (lane >> 4) * 4;

  for (int nt = 0; nt < NT; nt++) {
    bf16x8v b1[KS], b2[KS];
    #pragma unroll
    for (int ks = 0; ks < KS; ks++) {
      size_t boff = (size_t)(nt * KS + ks) * 64 * 8;
      b1[ks] = *reinterpret_cast<const bf16x8v*>(b1p + boff);
      b2[ks] = *reinterpret_cast<const bf16x8v*>(b2p + boff);
    }
    f32x4 acc1 = {}, acc2 = {};
    #pragma unroll
    for (int ks = 0; ks < KS; ks++) {
      acc1 = __builtin_amdgcn_mfma_f32_16x16x32_bf16(a[ks], b1[ks], acc1, 0, 0, 0);
      acc2 = __builtin_amdgcn_mfma_f32_16x16x32_bf16(a[ks], b2[ks], acc2, 0, 0, 0);
    }
    int col = nt * 16 + colb;
    bool cok = (col < H);
    float bias = cok ? tgb[col] : 0.f;
    #pragma unroll
    for (int q = 0; q < 4; q++) {
      int row = rbase + q;
      if (cok && row < NE) {
        hWb[(size_t)row * H + col] = f2b(acc1[q]);
        twb[(size_t)row * H + col] = f2b(sigmoidf(acc2[q] + bias));
      }
    }
  }
}

// aggregate + rrelu + l2norm + time gate + l2norm (+ hbnext emit), block id = b
DEVINL void aggfin_body(int b, const int* __restrict__ offs,
                        const unsigned int* __restrict__ se,
                        const bf16* __restrict__ hWb,
                        const unsigned short* __restrict__ relWb,
                        const bf16* __restrict__ twb,
                        float* __restrict__ h, float* __restrict__ evolve,
                        unsigned short* __restrict__ hbnext) {
  int wid = threadIdx.x >> 6, lane = threadIdx.x & 63;
  int i = b * 4 + wid;
  if (i >= NE) return;
  int s0 = offs[i], s1 = offs[i + 1];
  int d0 = lane * 4;
  bool act = d0 < H;
  const unsigned short* hw = (const unsigned short*)hWb;
  float a0 = 0.f, a1 = 0.f, a2 = 0.f, a3 = 0.f;

  int p = s0;
  for (; p + 4 <= s1; p += 4) {
    unsigned int e0 = se[p], e1 = se[p + 1], e2 = se[p + 2], e3 = se[p + 3];
    if (act) {
      ushort4 m0 = *reinterpret_cast<const ushort4*>(hw + (size_t)(e0 & 0xFFFFu) * H + d0);
      ushort4 m1 = *reinterpret_cast<const ushort4*>(hw + (size_t)(e1 & 0xFFFFu) * H + d0);
      ushort4 m2 = *reinterpret_cast<const ushort4*>(hw + (size_t)(e2 & 0xFFFFu) * H + d0);
      ushort4 m3 = *reinterpret_cast<const ushort4*>(hw + (size_t)(e3 & 0xFFFFu) * H + d0);
      ushort4 r0 = *reinterpret_cast<const ushort4*>(relWb + (size_t)(e0 >> 16) * H + d0);
      ushort4 r1 = *reinterpret_cast<const ushort4*>(relWb + (size_t)(e1 >> 16) * H + d0);
      ushort4 r2 = *reinterpret_cast<const ushort4*>(relWb + (size_t)(e2 >> 16) * H + d0);
      ushort4 r3 = *reinterpret_cast<const ushort4*>(relWb + (size_t)(e3 >> 16) * H + d0);
      a0 += u2f(m0.x) + u2f(r0.x) + u2f(m1.x) + u2f(r1.x)
          + u2f(m2.x) + u2f(r2.x) + u2f(m3.x) + u2f(r3.x);
      a1 += u2f(m0.y) + u2f(r0.y) + u2f(m1.y) + u2f(r1.y)
          + u2f(m2.y) + u2f(r2.y) + u2f(m3.y) + u2f(r3.y);
      a2 += u2f(m0.z) + u2f(r0.z) + u2f(m1.z) + u2f(r1.z)
          + u2f(m2.z) + u2f(r2.z) + u2f(m3.z) + u2f(r3.z);
      a3 += u2f(m0.w) + u2f(r0.w) + u2f(m1.w) + u2f(r1.w)
          + u2f(m2.w) + u2f(r2.w) + u2f(m3.w) + u2f(r3.w);
    }
  }
  for (; p < s1; p++) {
    unsigned int e0 = se[p];
    if (act) {
      ushort4 m0 = *reinterpret_cast<const ushort4*>(hw + (size_t)(e0 & 0xFFFFu) * H + d0);
      ushort4 r0 = *reinterpret_cast<const ushort4*>(relWb + (size_t)(e0 >> 16) * H + d0);
      a0 += u2f(m0.x) + u2f(r0.x);
      a1 += u2f(m0.y) + u2f(r0.y);
      a2 += u2f(m0.z) + u2f(r0.z);
      a3 += u2f(m0.w) + u2f(r0.w);
    }
  }

  int deg = s1 - s0;
  float nrm = deg > 0 ? 1.0f / (float)deg : 0.0f;
  float c0 = a0 * nrm; c0 = c0 >= 0.f ? c0 : SLOPE * c0;
  float c1 = a1 * nrm; c1 = c1 >= 0.f ? c1 : SLOPE * c1;
  float c2 = a2 * nrm; c2 = c2 >= 0.f ? c2 : SLOPE * c2;
  float c3 = a3 * nrm; c3 = c3 >= 0.f ? c3 : SLOPE * c3;
  float ss = act ? (c0 * c0 + c1 * c1 + c2 * c2 + c3 * c3) : 0.f;
  ss = wave_sum(ss);
  float sc = 1.0f / fmaxf(sqrtf(ss), 1e-12f);
  c0 *= sc; c1 *= sc; c2 *= sc; c3 *= sc;

  // time gate + combine + l2norm
  float v0 = 0.f, v1 = 0.f, v2 = 0.f, v3 = 0.f;
  if (act) {
    ushort4 t4 = *reinterpret_cast<const ushort4*>((const unsigned short*)twb + (size_t)i * H + d0);
    float4 hv = *reinterpret_cast<const float4*>(h + (size_t)i * H + d0);
    float t0 = u2f(t4.x), t1 = u2f(t4.y), t2 = u2f(t4.z), t3 = u2f(t4.w);
    v0 = t0 * c0 + (1.0f - t0) * hv.x;
    v1 = t1 * c1 + (1.0f - t1) * hv.y;
    v2 = t2 * c2 + (1.0f - t2) * hv.z;
    v3 = t3 * c3 + (1.0f - t3) * hv.w;
  }
  float ss2 = v0 * v0 + v1 * v1 + v2 * v2 + v3 * v3;
  ss2 = wave_sum(ss2);
  float sc2 = 1.0f / fmaxf(sqrtf(ss2), 1e-12f);
  if (act) {
    float4 o = make_float4(v0 * sc2, v1 * sc2, v2 * sc2, v3 * sc2);
    *reinterpret_cast<float4*>(h + (size_t)i * H + d0) = o;
    *reinterpret_cast<float4*>(evolve + (size_t)i * H + d0) = o;
    if (hbnext) {
      ushort4 ob; ob.x = f2bu(o.x); ob.y = f2bu(o.y); ob.z = f2bu(o.z); ob.w = f2bu(o.w);
      *reinterpret_cast<ushort4*>(hbnext + (size_t)i * KP + d0) = ob;
    }
  } else if (d0 < KP && hbnext) {
    ushort4 z; z.x = z.y = z.z = z.w = 0;
    *reinterpret_cast<ushort4*>(hbnext + (size_t)i * KP + d0) = z;
  }
}

// GRU A-matrix build, block id = b
DEVINL void a2b_body(int b, const float* __restrict__ er, const float* __restrict__ sums,
                     const int* __restrict__ segstart, const float* __restrict__ h0,
                     unsigned short* __restrict__ xcatb, unsigned short* __restrict__ h0b) {
  int i = b * 256 + threadIdx.x;
  const int n1 = GR * 416;
  if (i < n1) {
    int r = i / 416, c = i % 416;
    float v = 0.f;
    if (r < R2C) {
      if (c < H) v = er[r * H + c];
      else if (c < 2 * H) {
        int cnt = segstart[r + 1] - segstart[r];
        float inv = cnt > 0 ? 1.0f / (float)cnt : 0.0f;
        v = sums[r * H + (c - H)] * inv;
      }
    }
    xcatb[i] = f2bu(v);
  } else {
    int i2 = i - n1;
    if (i2 < GR * 224) {
      int r = i2 / 224, c = i2 % 224;
      float v = (r < R2C && c < H) ? h0[r * H + c] : 0.f;
      h0b[i2] = f2bu(v);
    }
  }
}

// ---------------- fused: node GEMM (blocks 0..781) + relsums (rest) ----------------
__global__ __launch_bounds__(256) void k_rsgemm(const int* __restrict__ rseg,
                                                const int* __restrict__ rte,
                                                const unsigned short* __restrict__ hb,
                                                float* __restrict__ sums,
                                                const unsigned short* __restrict__ bpack,
                                                const float* __restrict__ tgb,
                                                bf16* __restrict__ hWb,
                                                bf16* __restrict__ twb) {
  if (blockIdx.x < GB_GEMM)
    gemm_body(blockIdx.x, hb, bpack, tgb, hWb, twb);
  else
    relsums_body(blockIdx.x - GB_GEMM, rseg, rte, hb, sums);
}

// ---------------- fused: aggfin (blocks 0..12499) + a2b (rest) ----------------
__global__ __launch_bounds__(256) void k_afa2b(const int* __restrict__ offs,
                                               const unsigned int* __restrict__ se,
                                               const bf16* __restrict__ hWb,
                                               const unsigned short* __restrict__ relWb,
                                               const bf16* __restrict__ twb,
                                               float* __restrict__ h,
                                               float* __restrict__ evolve,
                                               unsigned short* __restrict__ hbnext,
                                               const float* __restrict__ er,
                                               const float* __restrict__ sums,
                                               const int* __restrict__ segstart,
                                               const float* __restrict__ h0,
                                               unsigned short* __restrict__ xcatb,
                                               unsigned short* __restrict__ h0b) {
  if (blockIdx.x < GB_AGG)
    aggfin_body(blockIdx.x, offs, se, hWb, relWb, twb, h, evolve, hbnext);
  else
    a2b_body(blockIdx.x - GB_AGG, er, sums, segstart, h0, xcatb, h0b);
}

// ---------------- per-step: GRU GEMMs via MFMA -> gi, gh [512][608] f32 ----------------
__global__ __launch_bounds__(256) void k_grumm(const unsigned short* __restrict__ xcatb,
                                               const unsigned short* __restrict__ h0b,
                                               const unsigned short* __restrict__ bgi,
                                               const unsigned short* __restrict__ bgh,
                                               float* __restrict__ gi_ws,
                                               float* __restrict__ gh_ws) {
  int wid = threadIdx.x >> 6, lane = threadIdx.x & 63;
  int nt   = blockIdx.x % GNT;
  int row0 = (blockIdx.x / GNT) * 64 + wid * 16;
  int arow = row0 + (lane & 15);

  const unsigned short* api = xcatb + (size_t)arow * 416 + (lane >> 4) * 8;
  bf16x8v ai[GKI];
  #pragma unroll
  for (int ks = 0; ks < GKI; ks++)
    ai[ks] = *reinterpret_cast<const bf16x8v*>(api + ks * 32);
  const unsigned short* aph = h0b + (size_t)arow * 224 + (lane >> 4) * 8;
  bf16x8v ah[GKH];
  #pragma unroll
  for (int ks = 0; ks < GKH; ks++)
    ah[ks] = *reinterpret_cast<const bf16x8v*>(aph + ks * 32);

  const unsigned short* bip = bgi + ((size_t)(nt * GKI) * 64 + lane) * 8;
  bf16x8v bi[GKI];
  #pragma unroll
  for (int ks = 0; ks < GKI; ks++)
    bi[ks] = *reinterpret_cast<const bf16x8v*>(bip + (size_t)ks * 64 * 8);
  const unsigned short* bhp = bgh + ((size_t)(nt * GKH) * 64 + lane) * 8;
  bf16x8v bh[GKH];
  #pragma unroll
  for (int ks = 0; ks < GKH; ks++)
    bh[ks] = *reinterpret_cast<const bf16x8v*>(bhp + (size_t)ks * 64 * 8);

  f32x4 a1 = {}, a2 = {};
  #pragma unroll
  for (int ks = 0; ks < GKI; ks++)
    a1 = __builtin_amdgcn_mfma_f32_16x16x32_bf16(ai[ks], bi[ks], a1, 0, 0, 0);
  #pragma unroll
  for (int ks = 0; ks < GKH; ks++)
    a2 = __builtin_amdgcn_mfma_f32_16x16x32_bf16(ah[ks], bh[ks], a2, 0, 0, 0);

  int col = nt * 16 + (lane & 15);
  int rb = row0 + (lane >> 4) * 4;
  #pragma unroll
  for (int q = 0; q < 4; q++) {
    gi_ws[(size_t)(rb + q) * GCS + col] = a1[q];
    gh_ws[(size_t)(rb + q) * GCS + col] = a2[q];
  }
}

// ---------------- per-step: GRU gates + l2norm -> h0 (and h0_out on last step) ----------------
__global__ __launch_bounds__(256) void k_grutail(const float* __restrict__ gi_ws,
                                                 const float* __restrict__ gh_ws,
                                                 const float* __restrict__ b_ih,
                                                 const float* __restrict__ b_hh,
                                                 float* __restrict__ h0,
                                                 float* __restrict__ h0_out) {
  __shared__ float xc[H];
  __shared__ float red[4];
  int r = blockIdx.x;
  int tid = threadIdx.x, wid = tid >> 6, lane = tid & 63;
  float ssp = 0.f;
  for (int d = tid; d < H; d += 256) {
    float gir = gi_ws[(size_t)r * GCS + d]         + b_ih[d];
    float ghr = gh_ws[(size_t)r * GCS + d]         + b_hh[d];
    float giz = gi_ws[(size_t)r * GCS + H + d]     + b_ih[H + d];
    float ghz = gh_ws[(size_t)r * GCS + H + d]     + b_hh[H + d];
    float gin = gi_ws[(size_t)r * GCS + 2 * H + d] + b_ih[2 * H + d];
    float ghn = gh_ws[(size_t)r * GCS + 2 * H + d] + b_hh[2 * H + d];
    float rg = sigmoidf(gir + ghr);
    float z  = sigmoidf(giz + ghz);
    float n  = tanhf(gin + rg * ghn);
    float hv = h0[r * H + d];
    float o  = (1.0f - z) * n + z * hv;
    xc[d] = o;
    ssp += o * o;
  }
  ssp = wave_sum(ssp);
  if (lane == 0) red[wid] = ssp;
  __syncthreads();
  float ss = red[0] + red[1] + red[2] + red[3];
  float sc = 1.0f / fmaxf(sqrtf(ss), 1e-12f);
  for (int d = tid; d < H; d += 256) {
    float o = xc[d] * sc;
    h0[r * H + d] = o;
    if (h0_out) h0_out[r * H + d] = o;
  }
}

extern "C" void kernel_launch(void* const* d_in, const int* in_sizes, int n_in,
                              void* d_out, int out_size, void* d_ws, size_t ws_size,
                              hipStream_t stream) {
  const float* de  = (const float*)d_in[0];
  const float* er  = (const float*)d_in[1];
  const float* wih = (const float*)d_in[2];
  const float* whh = (const float*)d_in[3];
  const float* bih = (const float*)d_in[4];
  const float* bhh = (const float*)d_in[5];
  const float* wn  = (const float*)d_in[6];
  const float* tg  = (const float*)d_in[7];
  const float* tgb = (const float*)d_in[8];
  const int* src  = (const int*)d_in[9];
  const int* dst  = (const int*)d_in[10];
  const int* et   = (const int*)d_in[11];
  const int* rte  = (const int*)d_in[12];
  const int* rseg = (const int*)d_in[13];

  char* w = (char*)d_ws;
  auto alloc = [&](size_t bytes) -> char* {
    char* p = w;
    w += (bytes + 255) / 256 * 256;
    return p;
  };
  float* h     = (float*)alloc(sizeof(float) * (size_t)NE * H);   // 40 MB
  bf16*  hWb   = (bf16*) alloc(sizeof(bf16)  * (size_t)NE * H);   // 20 MB
  bf16*  twb   = (bf16*) alloc(sizeof(bf16)  * (size_t)NE * H);   // 20 MB
  unsigned short* relWb = (unsigned short*)alloc(sizeof(unsigned short) * R2C * H); // 200 KB
  float* h0    = (float*)alloc(sizeof(float) * R2C * H);
  float* sums4 = (float*)alloc(sizeof(float) * TS * R2C * H);     // 1.6 MB
  unsigned short* bpack = (unsigned short*)alloc(sizeof(unsigned short) * 2 * NT * KS * 64 * 8); // 186 KB
  unsigned short* bgi   = (unsigned short*)alloc(sizeof(unsigned short) * GNT * GKI * 64 * 8);   // 506 KB
  unsigned short* bgh   = (unsigned short*)alloc(sizeof(unsigned short) * GNT * GKH * 64 * 8);   // 272 KB
  unsigned short* xcatb = (unsigned short*)alloc(sizeof(unsigned short) * GR * 416);             // 416 KB
  unsigned short* h0b   = (unsigned short*)alloc(sizeof(unsigned short) * GR * 224);             // 224 KB
  float* gi_ws = (float*)alloc(sizeof(float) * GR * GCS);          // 1.24 MB
  float* gh_ws = (float*)alloc(sizeof(float) * GR * GCS);          // 1.24 MB
  int* segstart4 = (int*)alloc(sizeof(int) * TS * (R2C + 1));
  int* deg4    = (int*) alloc(sizeof(int) * TS * NE);              // 800 KB
  int* offs4   = (int*) alloc(sizeof(int) * TS * (NE + 1));        // 800 KB
  int* cursor4 = (int*) alloc(sizeof(int) * TS * NE);              // 800 KB
  unsigned int* se4 = (unsigned int*)alloc(sizeof(unsigned int) * (size_t)TS * EC); // 6.4 MB
  int* bsums4  = (int*) alloc(sizeof(int) * TS * 256);
  (void)ws_size; (void)in_sizes; (void)n_in; (void)out_size;

  float* out    = (float*)d_out;
  float* evolve = out;                       // [TS, NE, H]
  float* h0out  = out + (size_t)TS * NE * H; // [R2C, H]

  const int gRow4  = (NE + 3) / 4;          // 12500
  const int gRel   = (R2C * H + 255) / 256; // 391
  const int gPack  = (2 * NT * KS * 64 + 255) / 256;       // 46
  const int gPackG = (GNT * (GKI + GKH) * 64 + 255) / 256; // 190
  const int gGru   = 8 * GNT;                              // 304
  const int gE4i   = (TS * EC / 4 + 255) / 256;            // 1563
  const int gZ4    = (TS * NE + 255) / 256;                // 782
  const int gZs    = (TS * R2C * H + 255) / 256;           // 1563
  const int gScat  = NCHK * TS * NRNG;                     // 12512

  // ---- prologue: init + weight packs + all-step CSR / segment bounds ----
  k_init_h<<<gRow4, 256, 0, stream>>>(de, h, (unsigned short*)evolve);  // hb0 in evolve[0] slot
  k_init_h0<<<gRel, 256, 0, stream>>>(er, h0);
  k_relw<<<R2C, 256, 0, stream>>>(er, wn, relWb);
  k_packb<<<gPack, 256, 0, stream>>>(wn, tg, bpack);
  k_packgru<<<gPackG, 256, 0, stream>>>(wih, whh, bgi, bgh);
  k_segbounds4<<<TS, 512, 0, stream>>>(rseg, segstart4);
  k_zero_f<<<gZs, 256, 0, stream>>>(sums4, TS * R2C * H);
  k_zero_i<<<gZ4, 256, 0, stream>>>(deg4, TS * NE);
  k_hist4<<<gE4i, 256, 0, stream>>>(dst, deg4);
  k_scan1<<<TS * NSCAN, 256, 0, stream>>>(deg4, offs4, bsums4);
  k_scan2<<<TS, 256, 0, stream>>>(bsums4);
  k_scan3<<<TS * NSCAN, 256, 0, stream>>>(offs4, bsums4, cursor4);
  k_scatter8<<<gScat, 256, 0, stream>>>(dst, src, et, cursor4, se4);

  for (int t = 0; t < TS; t++) {
    const int* rseg_t = rseg + (size_t)t * EC;
    const int* rte_t  = rte  + (size_t)t * EC;
    float* sums_t = sums4 + (size_t)t * R2C * H;
    float* evo_t = evolve + (size_t)t * NE * H;
    // hb(t) lives in the evolve[t] slot (written by k_init_h for t=0, else by
    // the previous step's aggfin); it is dead before aggfin overwrites it.
    unsigned short* hb = (unsigned short*)evo_t;
    unsigned short* hbnext = (t < TS - 1) ? (unsigned short*)(evolve + (size_t)(t + 1) * NE * H)
                                          : (unsigned short*)nullptr;

    // fused: node GEMM (MFMA) ∥ relation-segment sums (latency-bound gather)
    k_rsgemm<<<GB_GEMM + GB_RELS, 256, 0, stream>>>(rseg_t, rte_t, hb, sums_t,
                                                    bpack, tgb, hWb, twb);

    // fused: aggregate+timegate (writes h, evolve[t], hbnext) ∥ GRU A-matrix build
    // (a2b reads pre-update h0 — grutail runs after)
    k_afa2b<<<GB_AGG + GB_A2B, 256, 0, stream>>>(offs4 + t * (NE + 1), se4 + (size_t)t * EC,
                                                 hWb, relWb, twb, h, evo_t, hbnext,
                                                 er, sums_t, segstart4 + t * (R2C + 1),
                                                 h0, xcatb, h0b);

    // GRU GEMMs + gates (updates h0; h0_out on last step)
    k_grumm<<<gGru, 256, 0, stream>>>(xcatb, h0b, bgi, bgh, gi_ws, gh_ws);
    k_grutail<<<R2C, 256, 0, stream>>>(gi_ws, gh_ws, bih, bhh,
                                       h0, (t == TS - 1) ? h0out : (float*)nullptr);
  }
}

// Round 17
// 688.324 us; speedup vs baseline: 1.0722x; 1.0103x over previous
//
#include <hip/hip_runtime.h>
#include <hip/hip_bf16.h>

using bf16 = __hip_bfloat16;

constexpr int NE  = 50000;   // entities
constexpr int H   = 200;     // hidden dim
constexpr int R2C = 500;     // 2*num_rels
constexpr int TS  = 4;       // timesteps
constexpr int EC  = 400000;  // edges per step
constexpr float SLOPE = 0.22916666666666666f;  // rrelu eval slope
constexpr int NSCAN = (NE + 255) / 256;        // 196

// node-GEMM MFMA geometry
constexpr int KP = 224;      // K padded to 7*32
constexpr int KS = 7;        // k-steps of 32
constexpr int NT = 13;       // n-tiles of 16

// GRU-GEMM MFMA geometry (out [512][608])
constexpr int GNT = 38;      // n-tiles (608/16)
constexpr int GKI = 13;      // k-steps for W_ih (416/32)
constexpr int GKH = 7;       // k-steps for W_hh (224/32)
constexpr int GR  = 512;     // padded relation rows
constexpr int GCS = 608;     // padded gate cols (stride)

constexpr int RCH = 64;      // edges per block in relsums part
constexpr int NRNG = 8;      // dst ranges (≈ XCD count); NE/NRNG = 6250
constexpr int DRNG = NE / NRNG;              // 6250
constexpr int SCHK = 1024;   // edges per scatter chunk
constexpr int NCHK = (EC + SCHK - 1) / SCHK; // 391
constexpr int GSCAT = NCHK * TS * NRNG;      // 12512

// fused-kernel block counts
constexpr int GB_GEMM  = (NE + 63) / 64;     // 782
constexpr int GB_RELS  = EC / RCH;           // 6250
constexpr int GB_AGG   = (NE + 3) / 4;       // 12500
constexpr int GB_A2B   = (GR * 416 + GR * 224 + 255) / 256; // 1280

// prologue block layout
constexpr int PB_INITH  = (NE + 3) / 4;                       // 12500
constexpr int PB_INITH0 = (R2C * H + 255) / 256;              // 391
constexpr int PB_RELW   = R2C;                                // 500
constexpr int PB_PACKB  = (2 * NT * KS * 64 + 255) / 256;     // 46
constexpr int PB_PACKG  = (GNT * (GKI + GKH) * 64 + 255) / 256; // 190
constexpr int PB_SEGB   = TS;                                 // 4
constexpr int PB_ZS     = (TS * R2C * H + 255) / 256;         // 1563
constexpr int PB_ZI     = (TS * NE + 255) / 256;              // 782
constexpr int PO0 = PB_INITH;
constexpr int PO1 = PO0 + PB_INITH0;
constexpr int PO2 = PO1 + PB_RELW;
constexpr int PO3 = PO2 + PB_PACKB;
constexpr int PO4 = PO3 + PB_PACKG;
constexpr int PO5 = PO4 + PB_SEGB;
constexpr int PO6 = PO5 + PB_ZS;
constexpr int PO7 = PO6 + PB_ZI;   // total prologue blocks = 15976

#define DEVINL __device__ __forceinline__

typedef __bf16 bf16x8v __attribute__((ext_vector_type(8)));
typedef float  f32x4   __attribute__((ext_vector_type(4)));

DEVINL float b2f(bf16 v) { return __bfloat162float(v); }
DEVINL bf16  f2b(float v) { return __float2bfloat16(v); }
DEVINL unsigned short f2bu(float x) { bf16 b = f2b(x); return *reinterpret_cast<unsigned short*>(&b); }
DEVINL float u2f(unsigned short u) { unsigned int w = (unsigned int)u << 16; float f; __builtin_memcpy(&f, &w, 4); return f; }

DEVINL float wave_sum(float v) {
  #pragma unroll
  for (int o = 32; o > 0; o >>= 1) v += __shfl_xor(v, o, 64);
  return v;
}

DEVINL float sigmoidf(float x) { return 1.0f / (1.0f + expf(-x)); }

// ================= prologue bodies =================

DEVINL void inith_body(int b, const float* __restrict__ de, float* __restrict__ h,
                       unsigned short* __restrict__ hb0) {
  int wid = threadIdx.x >> 6, lane = threadIdx.x & 63;
  int row = b * 4 + wid;
  if (row >= NE) return;
  int d0 = lane * 4;
  bool act = d0 < H;
  float4 v = make_float4(0.f, 0.f, 0.f, 0.f);
  if (act) v = *reinterpret_cast<const float4*>(de + (size_t)row * H + d0);
  float ss = v.x * v.x + v.y * v.y + v.z * v.z + v.w * v.w;
  ss = wave_sum(ss);
  float sc = 1.0f / fmaxf(sqrtf(ss), 1e-12f);
  if (act) {
    float4 o = make_float4(v.x * sc, v.y * sc, v.z * sc, v.w * sc);
    *reinterpret_cast<float4*>(h + (size_t)row * H + d0) = o;
    ushort4 ob; ob.x = f2bu(o.x); ob.y = f2bu(o.y); ob.z = f2bu(o.z); ob.w = f2bu(o.w);
    *reinterpret_cast<ushort4*>(hb0 + (size_t)row * KP + d0) = ob;
  } else if (d0 < KP) {
    ushort4 z; z.x = z.y = z.z = z.w = 0;
    *reinterpret_cast<ushort4*>(hb0 + (size_t)row * KP + d0) = z;
  }
}

DEVINL void inith0_body(int b, const float* er, float* h0) {
  int i = b * 256 + threadIdx.x;
  if (i < R2C * H) h0[i] = er[i];
}

DEVINL void relw_body(int b, const float* er, const float* wn, unsigned short* relWb) {
  __shared__ float a[H];
  int r = b;
  for (int d = threadIdx.x; d < H; d += 256) a[d] = er[r * H + d];
  __syncthreads();
  for (int c = threadIdx.x; c < H; c += 256) {
    float s = 0.f;
    for (int k = 0; k < H; k++) s += a[k] * wn[k * H + c];
    relWb[r * H + c] = f2bu(s);
  }
}

DEVINL void packb_body(int b, const float* wn, const float* tg, unsigned short* bpack) {
  int t = b * 256 + threadIdx.x;
  int total = 2 * NT * KS * 64;
  if (t >= total) return;
  int m    = t / (NT * KS * 64);
  int rem  = t % (NT * KS * 64);
  int nt   = rem / (KS * 64);
  int rem2 = rem % (KS * 64);
  int ks   = rem2 / 64, lane = rem2 % 64;
  const float* W = m ? tg : wn;
  int n = nt * 16 + (lane & 15);
  unsigned short out[8];
  #pragma unroll
  for (int j = 0; j < 8; j++) {
    int k = ks * 32 + (lane >> 4) * 8 + j;
    float v = (k < H && n < H) ? W[k * H + n] : 0.f;
    out[j] = f2bu(v);
  }
  unsigned short* dst = bpack + (size_t)t * 8;
  #pragma unroll
  for (int j = 0; j < 8; j++) dst[j] = out[j];
}

DEVINL void packgru_body(int b, const float* __restrict__ wih, const float* __restrict__ whh,
                         unsigned short* __restrict__ bgi, unsigned short* __restrict__ bgh) {
  int t = b * 256 + threadIdx.x;
  const int tot_i = GNT * GKI * 64;
  const int tot_h = GNT * GKH * 64;
  if (t < tot_i) {
    int nt = t / (GKI * 64);
    int rem = t % (GKI * 64);
    int ks = rem / 64, lane = rem % 64;
    int n = nt * 16 + (lane & 15);
    unsigned short o[8];
    #pragma unroll
    for (int j = 0; j < 8; j++) {
      int k = ks * 32 + (lane >> 4) * 8 + j;
      o[j] = (n < 3 * H && k < 2 * H) ? f2bu(wih[n * (2 * H) + k]) : (unsigned short)0;
    }
    unsigned short* dstp = bgi + (size_t)t * 8;
    #pragma unroll
    for (int j = 0; j < 8; j++) dstp[j] = o[j];
  } else if (t < tot_i + tot_h) {
    int t2 = t - tot_i;
    int nt = t2 / (GKH * 64);
    int rem = t2 % (GKH * 64);
    int ks = rem / 64, lane = rem % 64;
    int n = nt * 16 + (lane & 15);
    unsigned short o[8];
    #pragma unroll
    for (int j = 0; j < 8; j++) {
      int k = ks * 32 + (lane >> 4) * 8 + j;
      o[j] = (n < 3 * H && k < H) ? f2bu(whh[n * H + k]) : (unsigned short)0;
    }
    unsigned short* dstp = bgh + (size_t)t2 * 8;
    #pragma unroll
    for (int j = 0; j < 8; j++) dstp[j] = o[j];
  }
}

DEVINL void segb_body(int b, const int* __restrict__ rseg, int* __restrict__ segstart4) {
  const int* rs = rseg + (size_t)b * EC;
  int* out = segstart4 + b * (R2C + 1);
  for (int r = threadIdx.x; r <= R2C; r += 256) {
    int lo = 0, hi = EC;
    while (lo < hi) { int m = (lo + hi) >> 1; if (rs[m] < r) lo = m + 1; else hi = m; }
    out[r] = lo;
  }
}

// fused prologue: all independent setup work in one launch
__global__ __launch_bounds__(256) void k_prologue(const float* __restrict__ de,
                                                  float* __restrict__ h,
                                                  unsigned short* __restrict__ hb0,
                                                  const float* __restrict__ er,
                                                  float* __restrict__ h0,
                                                  const float* __restrict__ wn,
                                                  unsigned short* __restrict__ relWb,
                                                  const float* __restrict__ tg,
                                                  unsigned short* __restrict__ bpack,
                                                  const float* __restrict__ wih,
                                                  const float* __restrict__ whh,
                                                  unsigned short* __restrict__ bgi,
                                                  unsigned short* __restrict__ bgh,
                                                  const int* __restrict__ rseg,
                                                  int* __restrict__ segstart4,
                                                  float* __restrict__ sums4,
                                                  int* __restrict__ deg4) {
  int b = blockIdx.x;
  if (b < PO0)       inith_body(b, de, h, hb0);
  else if (b < PO1)  inith0_body(b - PO0, er, h0);
  else if (b < PO2)  relw_body(b - PO1, er, wn, relWb);
  else if (b < PO3)  packb_body(b - PO2, wn, tg, bpack);
  else if (b < PO4)  packgru_body(b - PO3, wih, whh, bgi, bgh);
  else if (b < PO5)  segb_body(b - PO4, rseg, segstart4);
  else if (b < PO6) { int i = (b - PO5) * 256 + threadIdx.x; if (i < TS * R2C * H) sums4[i] = 0.f; }
  else              { int i = (b - PO6) * 256 + threadIdx.x; if (i < TS * NE) deg4[i] = 0; }
}

// ================= CSR build (hist + scans) =================

__global__ void k_hist4(const int* __restrict__ dst, int* __restrict__ deg4) {
  int base = (blockIdx.x * 256 + threadIdx.x) * 4;
  if (base + 3 < TS * EC) {
    int4 d4 = *reinterpret_cast<const int4*>(dst + base);
    int t = base / EC;   // EC%4==0, base%4==0 -> whole quad in one step
    atomicAdd(&deg4[t * NE + d4.x], 1);
    atomicAdd(&deg4[t * NE + d4.y], 1);
    atomicAdd(&deg4[t * NE + d4.z], 1);
    atomicAdd(&deg4[t * NE + d4.w], 1);
  }
}

__global__ __launch_bounds__(256) void k_scan1(const int* __restrict__ deg4,
                                               int* __restrict__ offs4,
                                               int* __restrict__ bsums4) {
  __shared__ int s[256];
  int t = blockIdx.x / NSCAN, blk = blockIdx.x % NSCAN;
  int i = blk * 256 + threadIdx.x;
  int v = (i < NE) ? deg4[t * NE + i] : 0;
  s[threadIdx.x] = v;
  __syncthreads();
  for (int o = 1; o < 256; o <<= 1) {
    int add = (threadIdx.x >= o) ? s[threadIdx.x - o] : 0;
    __syncthreads();
    s[threadIdx.x] += add;
    __syncthreads();
  }
  if (i < NE) offs4[t * (NE + 1) + i] = s[threadIdx.x] - v;  // exclusive
  if (threadIdx.x == 255) bsums4[t * 256 + blk] = s[255];
}

__global__ __launch_bounds__(256) void k_scan2(int* bsums4) {
  __shared__ int s[256];
  int t = blockIdx.x;
  int v = (threadIdx.x < NSCAN) ? bsums4[t * 256 + threadIdx.x] : 0;
  s[threadIdx.x] = v;
  __syncthreads();
  for (int o = 1; o < 256; o <<= 1) {
    int add = (threadIdx.x >= o) ? s[threadIdx.x - o] : 0;
    __syncthreads();
    s[threadIdx.x] += add;
    __syncthreads();
  }
  if (threadIdx.x < NSCAN) bsums4[t * 256 + threadIdx.x] = s[threadIdx.x] - v;  // exclusive
}

__global__ void k_scan3(int* __restrict__ offs4, const int* __restrict__ bsums4,
                        int* __restrict__ cursor4) {
  int t = blockIdx.x / NSCAN, blk = blockIdx.x % NSCAN;
  int i = blk * 256 + threadIdx.x;
  if (i < NE) {
    int o = offs4[t * (NE + 1) + i] + bsums4[t * 256 + blk];
    offs4[t * (NE + 1) + i] = o;
    cursor4[t * NE + i] = o;
  }
  if (blk == 0 && threadIdx.x == 0) offs4[t * (NE + 1) + NE] = EC;
}

// ================= device bodies for fused per-step kernels =================

// dst-range-partitioned scatter (XCD-local writes), block id = b
DEVINL void scatter_body(int b, const int* __restrict__ dst, const int* __restrict__ src,
                         const int* __restrict__ et, int* __restrict__ cursor4,
                         unsigned int* __restrict__ se4) {
  int r = b & (NRNG - 1);
  int rest = b >> 3;
  int t = rest % TS;
  int chunk = rest / TS;
  int li = chunk * SCHK + threadIdx.x * 4;
  if (li >= EC) return;                     // EC%4==0 so full quad when li<EC
  int base = t * EC + li;
  int4 d4 = *reinterpret_cast<const int4*>(dst + base);
  int4 s4 = *reinterpret_cast<const int4*>(src + base);
  int4 e4 = *reinterpret_cast<const int4*>(et + base);
  int* cur = cursor4 + t * NE;
  unsigned int* se = se4 + (size_t)t * EC;
  if ((unsigned)d4.x / DRNG == (unsigned)r) {
    int p = atomicAdd(&cur[d4.x], 1);
    se[p] = (unsigned int)s4.x | ((unsigned int)e4.x << 16);
  }
  if ((unsigned)d4.y / DRNG == (unsigned)r) {
    int p = atomicAdd(&cur[d4.y], 1);
    se[p] = (unsigned int)s4.y | ((unsigned int)e4.y << 16);
  }
  if ((unsigned)d4.z / DRNG == (unsigned)r) {
    int p = atomicAdd(&cur[d4.z], 1);
    se[p] = (unsigned int)s4.z | ((unsigned int)e4.z << 16);
  }
  if ((unsigned)d4.w / DRNG == (unsigned)r) {
    int p = atomicAdd(&cur[d4.w], 1);
    se[p] = (unsigned int)s4.w | ((unsigned int)e4.w << 16);
  }
}

// segment-sum over sorted rseg, block id = b
DEVINL void relsums_body(int b, const int* __restrict__ rseg, const int* __restrict__ rte,
                         const unsigned short* __restrict__ hb, float* __restrict__ sums) {
  int base = b * RCH;
  int d = threadIdx.x;
  bool act = d < H;
  float a0 = 0.f, a1 = 0.f, a2 = 0.f, a3 = 0.f;
  int prev = rseg[base];
  for (int g = 0; g < RCH; g += 8) {
    int e = base + g;
    int4 sgA = *reinterpret_cast<const int4*>(rseg + e);
    int4 sgB = *reinterpret_cast<const int4*>(rseg + e + 4);
    int4 rrA = *reinterpret_cast<const int4*>(rte + e);
    int4 rrB = *reinterpret_cast<const int4*>(rte + e + 4);
    if (sgB.w == prev) {           // sorted => whole group of 8 in same segment
      if (act) {
        float v0 = u2f(hb[(size_t)rrA.x * KP + d]);
        float v1 = u2f(hb[(size_t)rrA.y * KP + d]);
        float v2 = u2f(hb[(size_t)rrA.z * KP + d]);
        float v3 = u2f(hb[(size_t)rrA.w * KP + d]);
        float v4 = u2f(hb[(size_t)rrB.x * KP + d]);
        float v5 = u2f(hb[(size_t)rrB.y * KP + d]);
        float v6 = u2f(hb[(size_t)rrB.z * KP + d]);
        float v7 = u2f(hb[(size_t)rrB.w * KP + d]);
        a0 += v0; a1 += v1; a2 += v2; a3 += v3;
        a0 += v4; a1 += v5; a2 += v6; a3 += v7;
      }
    } else {                       // boundary group (rare): scalar path
      int ss[8] = {sgA.x, sgA.y, sgA.z, sgA.w, sgB.x, sgB.y, sgB.z, sgB.w};
      int rr[8] = {rrA.x, rrA.y, rrA.z, rrA.w, rrB.x, rrB.y, rrB.z, rrB.w};
      #pragma unroll
      for (int j = 0; j < 8; j++) {
        if (ss[j] != prev) {
          if (act) atomicAdd(&sums[prev * H + d], a0 + a1 + a2 + a3);
          a0 = a1 = a2 = a3 = 0.f;
          prev = ss[j];
        }
        if (act) a0 += u2f(hb[(size_t)rr[j] * KP + d]);
      }
    }
  }
  if (act) atomicAdd(&sums[prev * H + d], a0 + a1 + a2 + a3);
}

// node GEMMs via MFMA, block id = b
DEVINL void gemm_body(int b, const unsigned short* __restrict__ hb,
                      const unsigned short* __restrict__ bpack,
                      const float* __restrict__ tgb,
                      bf16* __restrict__ hWb, bf16* __restrict__ twb) {
  int wid = threadIdx.x >> 6, lane = threadIdx.x & 63;
  int row0 = b * 64 + wid * 16;
  if (row0 >= NE) return;                 // wave-uniform
  int arow = min(row0 + (lane & 15), NE - 1);
  const unsigned short* ap = hb + (size_t)arow * KP + (lane >> 4) * 8;
  bf16x8v a[KS];
  #pragma unroll
  for (int ks = 0; ks < KS; ks++)
    a[ks] = *reinterpret_cast<const bf16x8v*>(ap + ks * 32);

  const unsigned short* b1p = bpack + (size_t)lane * 8;
  const unsigned short* b2p = b1p + (size_t)NT * KS * 64 * 8;
  int colb = lane & 15;
  int rbase = row0 + (lane >> 4) * 4;

  for (int nt = 0; nt < NT; nt++) {
    bf16x8v b1[KS], b2[KS];
    #pragma unroll
    for (int ks = 0; ks < KS; ks++) {
      size_t boff = (size_t)(nt * KS + ks) * 64 * 8;
      b1[ks] = *reinterpret_cast<const bf16x8v*>(b1p + boff);
      b2[ks] = *reinterpret_cast<const bf16x8v*>(b2p + boff);
    }
    f32x4 acc1 = {}, acc2 = {};
    #pragma unroll
    for (int ks = 0; ks < KS; ks++) {
      acc1 = __builtin_amdgcn_mfma_f32_16x16x32_bf16(a[ks], b1[ks], acc1, 0, 0, 0);
      acc2 = __builtin_amdgcn_mfma_f32_16x16x32_bf16(a[ks], b2[ks], acc2, 0, 0, 0);
    }
    int col = nt * 16 + colb;
    bool cok = (col < H);
    float bias = cok ? tgb[col] : 0.f;
    #pragma unroll
    for (int q = 0; q < 4; q++) {
      int row = rbase + q;
      if (cok && row < NE) {
        hWb[(size_t)row * H + col] = f2b(acc1[q]);
        twb[(size_t)row * H + col] = f2b(sigmoidf(acc2[q] + bias));
      }
    }
  }
}

// aggregate + rrelu + l2norm + time gate + l2norm (+ hbnext emit), block id = b
DEVINL void aggfin_body(int b, const int* __restrict__ offs,
                        const unsigned int* __restrict__ se,
                        const bf16* __restrict__ hWb,
                        const unsigned short* __restrict__ relWb,
                        const bf16* __restrict__ twb,
                        float* __restrict__ h, float* __restrict__ evolve,
                        unsigned short* __restrict__ hbnext) {
  int wid = threadIdx.x >> 6, lane = threadIdx.x & 63;
  int i = b * 4 + wid;
  if (i >= NE) return;
  int s0 = offs[i], s1 = offs[i + 1];
  int d0 = lane * 4;
  bool act = d0 < H;
  const unsigned short* hw = (const unsigned short*)hWb;
  float a0 = 0.f, a1 = 0.f, a2 = 0.f, a3 = 0.f;

  int p = s0;
  for (; p + 4 <= s1; p += 4) {
    unsigned int e0 = se[p], e1 = se[p + 1], e2 = se[p + 2], e3 = se[p + 3];
    if (act) {
      ushort4 m0 = *reinterpret_cast<const ushort4*>(hw + (size_t)(e0 & 0xFFFFu) * H + d0);
      ushort4 m1 = *reinterpret_cast<const ushort4*>(hw + (size_t)(e1 & 0xFFFFu) * H + d0);
      ushort4 m2 = *reinterpret_cast<const ushort4*>(hw + (size_t)(e2 & 0xFFFFu) * H + d0);
      ushort4 m3 = *reinterpret_cast<const ushort4*>(hw + (size_t)(e3 & 0xFFFFu) * H + d0);
      ushort4 r0 = *reinterpret_cast<const ushort4*>(relWb + (size_t)(e0 >> 16) * H + d0);
      ushort4 r1 = *reinterpret_cast<const ushort4*>(relWb + (size_t)(e1 >> 16) * H + d0);
      ushort4 r2 = *reinterpret_cast<const ushort4*>(relWb + (size_t)(e2 >> 16) * H + d0);
      ushort4 r3 = *reinterpret_cast<const ushort4*>(relWb + (size_t)(e3 >> 16) * H + d0);
      a0 += u2f(m0.x) + u2f(r0.x) + u2f(m1.x) + u2f(r1.x)
          + u2f(m2.x) + u2f(r2.x) + u2f(m3.x) + u2f(r3.x);
      a1 += u2f(m0.y) + u2f(r0.y) + u2f(m1.y) + u2f(r1.y)
          + u2f(m2.y) + u2f(r2.y) + u2f(m3.y) + u2f(r3.y);
      a2 += u2f(m0.z) + u2f(r0.z) + u2f(m1.z) + u2f(r1.z)
          + u2f(m2.z) + u2f(r2.z) + u2f(m3.z) + u2f(r3.z);
      a3 += u2f(m0.w) + u2f(r0.w) + u2f(m1.w) + u2f(r1.w)
          + u2f(m2.w) + u2f(r2.w) + u2f(m3.w) + u2f(r3.w);
    }
  }
  for (; p < s1; p++) {
    unsigned int e0 = se[p];
    if (act) {
      ushort4 m0 = *reinterpret_cast<const ushort4*>(hw + (size_t)(e0 & 0xFFFFu) * H + d0);
      ushort4 r0 = *reinterpret_cast<const ushort4*>(relWb + (size_t)(e0 >> 16) * H + d0);
      a0 += u2f(m0.x) + u2f(r0.x);
      a1 += u2f(m0.y) + u2f(r0.y);
      a2 += u2f(m0.z) + u2f(r0.z);
      a3 += u2f(m0.w) + u2f(r0.w);
    }
  }

  int deg = s1 - s0;
  float nrm = deg > 0 ? 1.0f / (float)deg : 0.0f;
  float c0 = a0 * nrm; c0 = c0 >= 0.f ? c0 : SLOPE * c0;
  float c1 = a1 * nrm; c1 = c1 >= 0.f ? c1 : SLOPE * c1;
  float c2 = a2 * nrm; c2 = c2 >= 0.f ? c2 : SLOPE * c2;
  float c3 = a3 * nrm; c3 = c3 >= 0.f ? c3 : SLOPE * c3;
  float ss = act ? (c0 * c0 + c1 * c1 + c2 * c2 + c3 * c3) : 0.f;
  ss = wave_sum(ss);
  float sc = 1.0f / fmaxf(sqrtf(ss), 1e-12f);
  c0 *= sc; c1 *= sc; c2 *= sc; c3 *= sc;

  // time gate + combine + l2norm
  float v0 = 0.f, v1 = 0.f, v2 = 0.f, v3 = 0.f;
  if (act) {
    ushort4 t4 = *reinterpret_cast<const ushort4*>((const unsigned short*)twb + (size_t)i * H + d0);
    float4 hv = *reinterpret_cast<const float4*>(h + (size_t)i * H + d0);
    float t0 = u2f(t4.x), t1 = u2f(t4.y), t2 = u2f(t4.z), t3 = u2f(t4.w);
    v0 = t0 * c0 + (1.0f - t0) * hv.x;
    v1 = t1 * c1 + (1.0f - t1) * hv.y;
    v2 = t2 * c2 + (1.0f - t2) * hv.z;
    v3 = t3 * c3 + (1.0f - t3) * hv.w;
  }
  float ss2 = v0 * v0 + v1 * v1 + v2 * v2 + v3 * v3;
  ss2 = wave_sum(ss2);
  float sc2 = 1.0f / fmaxf(sqrtf(ss2), 1e-12f);
  if (act) {
    float4 o = make_float4(v0 * sc2, v1 * sc2, v2 * sc2, v3 * sc2);
    *reinterpret_cast<float4*>(h + (size_t)i * H + d0) = o;
    *reinterpret_cast<float4*>(evolve + (size_t)i * H + d0) = o;
    if (hbnext) {
      ushort4 ob; ob.x = f2bu(o.x); ob.y = f2bu(o.y); ob.z = f2bu(o.z); ob.w = f2bu(o.w);
      *reinterpret_cast<ushort4*>(hbnext + (size_t)i * KP + d0) = ob;
    }
  } else if (d0 < KP && hbnext) {
    ushort4 z; z.x = z.y = z.z = z.w = 0;
    *reinterpret_cast<ushort4*>(hbnext + (size_t)i * KP + d0) = z;
  }
}

// GRU A-matrix build, block id = b
DEVINL void a2b_body(int b, const float* __restrict__ er, const float* __restrict__ sums,
                     const int* __restrict__ segstart, const float* __restrict__ h0,
                     unsigned short* __restrict__ xcatb, unsigned short* __restrict__ h0b) {
  int i = b * 256 + threadIdx.x;
  const int n1 = GR * 416;
  if (i < n1) {
    int r = i / 416, c = i % 416;
    float v = 0.f;
    if (r < R2C) {
      if (c < H) v = er[r * H + c];
      else if (c < 2 * H) {
        int cnt = segstart[r + 1] - segstart[r];
        float inv = cnt > 0 ? 1.0f / (float)cnt : 0.0f;
        v = sums[r * H + (c - H)] * inv;
      }
    }
    xcatb[i] = f2bu(v);
  } else {
    int i2 = i - n1;
    if (i2 < GR * 224) {
      int r = i2 / 224, c = i2 % 224;
      float v = (r < R2C && c < H) ? h0[r * H + c] : 0.f;
      h0b[i2] = f2bu(v);
    }
  }
}

// ---------------- fused: node GEMM + relsums (+ optional scatter for t=0) ----------------
__global__ __launch_bounds__(256) void k_rsgemm(const int* __restrict__ rseg,
                                                const int* __restrict__ rte,
                                                const unsigned short* __restrict__ hb,
                                                float* __restrict__ sums,
                                                const unsigned short* __restrict__ bpack,
                                                const float* __restrict__ tgb,
                                                bf16* __restrict__ hWb,
                                                bf16* __restrict__ twb,
                                                const int* __restrict__ dst,
                                                const int* __restrict__ src,
                                                const int* __restrict__ et,
                                                int* __restrict__ cursor4,
                                                unsigned int* __restrict__ se4) {
  int b = blockIdx.x;
  if (b < GB_GEMM)
    gemm_body(b, hb, bpack, tgb, hWb, twb);
  else if (b < GB_GEMM + GB_RELS)
    relsums_body(b - GB_GEMM, rseg, rte, hb, sums);
  else
    scatter_body(b - (GB_GEMM + GB_RELS), dst, src, et, cursor4, se4);
}

// ---------------- fused: aggfin (blocks 0..12499) + a2b (rest) ----------------
__global__ __launch_bounds__(256) void k_afa2b(const int* __restrict__ offs,
                                               const unsigned int* __restrict__ se,
                                               const bf16* __restrict__ hWb,
                                               const unsigned short* __restrict__ relWb,
                                               const bf16* __restrict__ twb,
                                               float* __restrict__ h,
                                               float* __restrict__ evolve,
                                               unsigned short* __restrict__ hbnext,
                                               const float* __restrict__ er,
                                               const float* __restrict__ sums,
                                               const int* __restrict__ segstart,
                                               const float* __restrict__ h0,
                                               unsigned short* __restrict__ xcatb,
                                               unsigned short* __restrict__ h0b) {
  if (blockIdx.x < GB_AGG)
    aggfin_body(blockIdx.x, offs, se, hWb, relWb, twb, h, evolve, hbnext);
  else
    a2b_body(blockIdx.x - GB_AGG, er, sums, segstart, h0, xcatb, h0b);
}

// ---------------- per-step: GRU GEMMs via MFMA -> gi, gh [512][608] f32 ----------------
__global__ __launch_bounds__(256) void k_grumm(const unsigned short* __restrict__ xcatb,
                                               const unsigned short* __restrict__ h0b,
                                               const unsigned short* __restrict__ bgi,
                                               const unsigned short* __restrict__ bgh,
                                               float* __restrict__ gi_ws,
                                               float* __restrict__ gh_ws) {
  int wid = threadIdx.x >> 6, lane = threadIdx.x & 63;
  int nt   = blockIdx.x % GNT;
  int row0 = (blockIdx.x / GNT) * 64 + wid * 16;
  int arow = row0 + (lane & 15);

  const unsigned short* api = xcatb + (size_t)arow * 416 + (lane >> 4) * 8;
  bf16x8v ai[GKI];
  #pragma unroll
  for (int ks = 0; ks < GKI; ks++)
    ai[ks] = *reinterpret_cast<const bf16x8v*>(api + ks * 32);
  const unsigned short* aph = h0b + (size_t)arow * 224 + (lane >> 4) * 8;
  bf16x8v ah[GKH];
  #pragma unroll
  for (int ks = 0; ks < GKH; ks++)
    ah[ks] = *reinterpret_cast<const bf16x8v*>(aph + ks * 32);

  const unsigned short* bip = bgi + ((size_t)(nt * GKI) * 64 + lane) * 8;
  bf16x8v bi[GKI];
  #pragma unroll
  for (int ks = 0; ks < GKI; ks++)
    bi[ks] = *reinterpret_cast<const bf16x8v*>(bip + (size_t)ks * 64 * 8);
  const unsigned short* bhp = bgh + ((size_t)(nt * GKH) * 64 + lane) * 8;
  bf16x8v bh[GKH];
  #pragma unroll
  for (int ks = 0; ks < GKH; ks++)
    bh[ks] = *reinterpret_cast<const bf16x8v*>(bhp + (size_t)ks * 64 * 8);

  f32x4 a1 = {}, a2 = {};
  #pragma unroll
  for (int ks = 0; ks < GKI; ks++)
    a1 = __builtin_amdgcn_mfma_f32_16x16x32_bf16(ai[ks], bi[ks], a1, 0, 0, 0);
  #pragma unroll
  for (int ks = 0; ks < GKH; ks++)
    a2 = __builtin_amdgcn_mfma_f32_16x16x32_bf16(ah[ks], bh[ks], a2, 0, 0, 0);

  int col = nt * 16 + (lane & 15);
  int rb = row0 + (lane >> 4) * 4;
  #pragma unroll
  for (int q = 0; q < 4; q++) {
    gi_ws[(size_t)(rb + q) * GCS + col] = a1[q];
    gh_ws[(size_t)(rb + q) * GCS + col] = a2[q];
  }
}

// ---------------- per-step: GRU gates + l2norm -> h0 (and h0_out on last step) ----------------
__global__ __launch_bounds__(256) void k_grutail(const float* __restrict__ gi_ws,
                                                 const float* __restrict__ gh_ws,
                                                 const float* __restrict__ b_ih,
                                                 const float* __restrict__ b_hh,
                                                 float* __restrict__ h0,
                                                 float* __restrict__ h0_out) {
  __shared__ float xc[H];
  __shared__ float red[4];
  int r = blockIdx.x;
  int tid = threadIdx.x, wid = tid >> 6, lane = tid & 63;
  float ssp = 0.f;
  for (int d = tid; d < H; d += 256) {
    float gir = gi_ws[(size_t)r * GCS + d]         + b_ih[d];
    float ghr = gh_ws[(size_t)r * GCS + d]         + b_hh[d];
    float giz = gi_ws[(size_t)r * GCS + H + d]     + b_ih[H + d];
    float ghz = gh_ws[(size_t)r * GCS + H + d]     + b_hh[H + d];
    float gin = gi_ws[(size_t)r * GCS + 2 * H + d] + b_ih[2 * H + d];
    float ghn = gh_ws[(size_t)r * GCS + 2 * H + d] + b_hh[2 * H + d];
    float rg = sigmoidf(gir + ghr);
    float z  = sigmoidf(giz + ghz);
    float n  = tanhf(gin + rg * ghn);
    float hv = h0[r * H + d];
    float o  = (1.0f - z) * n + z * hv;
    xc[d] = o;
    ssp += o * o;
  }
  ssp = wave_sum(ssp);
  if (lane == 0) red[wid] = ssp;
  __syncthreads();
  float ss = red[0] + red[1] + red[2] + red[3];
  float sc = 1.0f / fmaxf(sqrtf(ss), 1e-12f);
  for (int d = tid; d < H; d += 256) {
    float o = xc[d] * sc;
    h0[r * H + d] = o;
    if (h0_out) h0_out[r * H + d] = o;
  }
}

extern "C" void kernel_launch(void* const* d_in, const int* in_sizes, int n_in,
                              void* d_out, int out_size, void* d_ws, size_t ws_size,
                              hipStream_t stream) {
  const float* de  = (const float*)d_in[0];
  const float* er  = (const float*)d_in[1];
  const float* wih = (const float*)d_in[2];
  const float* whh = (const float*)d_in[3];
  const float* bih = (const float*)d_in[4];
  const float* bhh = (const float*)d_in[5];
  const float* wn  = (const float*)d_in[6];
  const float* tg  = (const float*)d_in[7];
  const float* tgb = (const float*)d_in[8];
  const int* src  = (const int*)d_in[9];
  const int* dst  = (const int*)d_in[10];
  const int* et   = (const int*)d_in[11];
  const int* rte  = (const int*)d_in[12];
  const int* rseg = (const int*)d_in[13];

  char* w = (char*)d_ws;
  auto alloc = [&](size_t bytes) -> char* {
    char* p = w;
    w += (bytes + 255) / 256 * 256;
    return p;
  };
  float* h     = (float*)alloc(sizeof(float) * (size_t)NE * H);   // 40 MB
  bf16*  hWb   = (bf16*) alloc(sizeof(bf16)  * (size_t)NE * H);   // 20 MB
  bf16*  twb   = (bf16*) alloc(sizeof(bf16)  * (size_t)NE * H);   // 20 MB
  unsigned short* relWb = (unsigned short*)alloc(sizeof(unsigned short) * R2C * H); // 200 KB
  float* h0    = (float*)alloc(sizeof(float) * R2C * H);
  float* sums4 = (float*)alloc(sizeof(float) * TS * R2C * H);     // 1.6 MB
  unsigned short* bpack = (unsigned short*)alloc(sizeof(unsigned short) * 2 * NT * KS * 64 * 8); // 186 KB
  unsigned short* bgi   = (unsigned short*)alloc(sizeof(unsigned short) * GNT * GKI * 64 * 8);   // 506 KB
  unsigned short* bgh   = (unsigned short*)alloc(sizeof(unsigned short) * GNT * GKH * 64 * 8);   // 272 KB
  unsigned short* xcatb = (unsigned short*)alloc(sizeof(unsigned short) * GR * 416);             // 416 KB
  unsigned short* h0b   = (unsigned short*)alloc(sizeof(unsigned short) * GR * 224);             // 224 KB
  float* gi_ws = (float*)alloc(sizeof(float) * GR * GCS);          // 1.24 MB
  float* gh_ws = (float*)alloc(sizeof(float) * GR * GCS);          // 1.24 MB
  int* segstart4 = (int*)alloc(sizeof(int) * TS * (R2C + 1));
  int* deg4    = (int*) alloc(sizeof(int) * TS * NE);              // 800 KB
  int* offs4   = (int*) alloc(sizeof(int) * TS * (NE + 1));        // 800 KB
  int* cursor4 = (int*) alloc(sizeof(int) * TS * NE);              // 800 KB
  unsigned int* se4 = (unsigned int*)alloc(sizeof(unsigned int) * (size_t)TS * EC); // 6.4 MB
  int* bsums4  = (int*) alloc(sizeof(int) * TS * 256);
  (void)ws_size; (void)in_sizes; (void)n_in; (void)out_size;

  float* out    = (float*)d_out;
  float* evolve = out;                       // [TS, NE, H]
  float* h0out  = out + (size_t)TS * NE * H; // [R2C, H]

  const int gGru   = 8 * GNT;                              // 304
  const int gE4i   = (TS * EC / 4 + 255) / 256;            // 1563

  // ---- prologue: fused setup + CSR scan chain ----
  k_prologue<<<PO7, 256, 0, stream>>>(de, h, (unsigned short*)evolve, er, h0,
                                      wn, relWb, tg, bpack, wih, whh, bgi, bgh,
                                      rseg, segstart4, sums4, deg4);
  k_hist4<<<gE4i, 256, 0, stream>>>(dst, deg4);
  k_scan1<<<TS * NSCAN, 256, 0, stream>>>(deg4, offs4, bsums4);
  k_scan2<<<TS, 256, 0, stream>>>(bsums4);
  k_scan3<<<TS * NSCAN, 256, 0, stream>>>(offs4, bsums4, cursor4);

  for (int t = 0; t < TS; t++) {
    const int* rseg_t = rseg + (size_t)t * EC;
    const int* rte_t  = rte  + (size_t)t * EC;
    float* sums_t = sums4 + (size_t)t * R2C * H;
    float* evo_t = evolve + (size_t)t * NE * H;
    // hb(t) lives in the evolve[t] slot (written by init_h body for t=0, else by
    // the previous step's aggfin); it is dead before aggfin overwrites it.
    unsigned short* hb = (unsigned short*)evo_t;
    unsigned short* hbnext = (t < TS - 1) ? (unsigned short*)(evolve + (size_t)(t + 1) * NE * H)
                                          : (unsigned short*)nullptr;

    // fused: node GEMM (MFMA) ∥ relation-segment sums ∥ (t=0 only) CSR scatter
    int nblk = GB_GEMM + GB_RELS + (t == 0 ? GSCAT : 0);
    k_rsgemm<<<nblk, 256, 0, stream>>>(rseg_t, rte_t, hb, sums_t, bpack, tgb, hWb, twb,
                                       dst, src, et, cursor4, se4);

    // fused: aggregate+timegate (writes h, evolve[t], hbnext) ∥ GRU A-matrix build
    k_afa2b<<<GB_AGG + GB_A2B, 256, 0, stream>>>(offs4 + t * (NE + 1), se4 + (size_t)t * EC,
                                                 hWb, relWb, twb, h, evo_t, hbnext,
                                                 er, sums_t, segstart4 + t * (R2C + 1),
                                                 h0, xcatb, h0b);

    // GRU GEMMs + gates (updates h0; h0_out on last step)
    k_grumm<<<gGru, 256, 0, stream>>>(xcatb, h0b, bgi, bgh, gi_ws, gh_ws);
    k_grutail<<<R2C, 256, 0, stream>>>(gi_ws, gh_ws, bih, bhh,
                                       h0, (t == TS - 1) ? h0out : (float*)nullptr);
  }
}

// Round 18
// 674.507 us; speedup vs baseline: 1.0942x; 1.0205x over previous
//
#include <hip/hip_runtime.h>
#include <hip/hip_bf16.h>

using bf16 = __hip_bfloat16;

constexpr int NE  = 50000;   // entities
constexpr int H   = 200;     // hidden dim
constexpr int R2C = 500;     // 2*num_rels
constexpr int TS  = 4;       // timesteps
constexpr int EC  = 400000;  // edges per step
constexpr float SLOPE = 0.22916666666666666f;  // rrelu eval slope
constexpr int NSCAN = (NE + 255) / 256;        // 196

// node-GEMM MFMA geometry
constexpr int KP = 224;      // K padded to 7*32
constexpr int KS = 7;        // k-steps of 32
constexpr int NT = 13;       // n-tiles of 16

// GRU-GEMM MFMA geometry (out [512][608])
constexpr int GNT = 38;      // n-tiles (608/16)
constexpr int GKI = 13;      // k-steps for W_ih (416/32)
constexpr int GKH = 7;       // k-steps for W_hh (224/32)
constexpr int GR  = 512;     // padded relation rows
constexpr int GCS = 608;     // padded gate cols (stride)

constexpr int RCH = 64;      // edges per block in relsums part
constexpr int NRNG = 8;      // dst ranges (≈ XCD count); NE/NRNG = 6250
constexpr int DRNG = NE / NRNG;              // 6250
constexpr int SCHK = 1024;   // edges per scatter chunk
constexpr int NCHK = (EC + SCHK - 1) / SCHK; // 391
constexpr int GSCAT1 = NCHK * NRNG;          // 3128 (one step's scatter blocks)

// fused-kernel block counts
constexpr int GB_GEMM  = (NE + 63) / 64;     // 782
constexpr int GB_RELS  = EC / RCH;           // 6250
constexpr int GB_AGG   = (NE + 3) / 4;       // 12500
constexpr int GB_A2B   = (GR * 416 + GR * 224 + 255) / 256; // 1280

// prologue block layout
constexpr int PB_INITH  = (NE + 3) / 4;                       // 12500
constexpr int PB_INITH0 = (R2C * H + 255) / 256;              // 391
constexpr int PB_RELW   = R2C;                                // 500
constexpr int PB_PACKB  = (2 * NT * KS * 64 + 255) / 256;     // 46
constexpr int PB_PACKG  = (GNT * (GKI + GKH) * 64 + 255) / 256; // 190
constexpr int PB_SEGB   = TS;                                 // 4
constexpr int PB_ZS     = (TS * R2C * H + 255) / 256;         // 1563
constexpr int PB_ZI     = (TS * NE + 255) / 256;              // 782
constexpr int PO0 = PB_INITH;
constexpr int PO1 = PO0 + PB_INITH0;
constexpr int PO2 = PO1 + PB_RELW;
constexpr int PO3 = PO2 + PB_PACKB;
constexpr int PO4 = PO3 + PB_PACKG;
constexpr int PO5 = PO4 + PB_SEGB;
constexpr int PO6 = PO5 + PB_ZS;
constexpr int PO7 = PO6 + PB_ZI;   // total prologue blocks = 15976

#define DEVINL __device__ __forceinline__

typedef __bf16 bf16x8v __attribute__((ext_vector_type(8)));
typedef float  f32x4   __attribute__((ext_vector_type(4)));

DEVINL float b2f(bf16 v) { return __bfloat162float(v); }
DEVINL bf16  f2b(float v) { return __float2bfloat16(v); }
DEVINL unsigned short f2bu(float x) { bf16 b = f2b(x); return *reinterpret_cast<unsigned short*>(&b); }
DEVINL float u2f(unsigned short u) { unsigned int w = (unsigned int)u << 16; float f; __builtin_memcpy(&f, &w, 4); return f; }

DEVINL float wave_sum(float v) {
  #pragma unroll
  for (int o = 32; o > 0; o >>= 1) v += __shfl_xor(v, o, 64);
  return v;
}

DEVINL float sigmoidf(float x) { return 1.0f / (1.0f + expf(-x)); }

// ================= prologue bodies =================

DEVINL void inith_body(int b, const float* __restrict__ de, float* __restrict__ h,
                       unsigned short* __restrict__ hb0) {
  int wid = threadIdx.x >> 6, lane = threadIdx.x & 63;
  int row = b * 4 + wid;
  if (row >= NE) return;
  int d0 = lane * 4;
  bool act = d0 < H;
  float4 v = make_float4(0.f, 0.f, 0.f, 0.f);
  if (act) v = *reinterpret_cast<const float4*>(de + (size_t)row * H + d0);
  float ss = v.x * v.x + v.y * v.y + v.z * v.z + v.w * v.w;
  ss = wave_sum(ss);
  float sc = 1.0f / fmaxf(sqrtf(ss), 1e-12f);
  if (act) {
    float4 o = make_float4(v.x * sc, v.y * sc, v.z * sc, v.w * sc);
    *reinterpret_cast<float4*>(h + (size_t)row * H + d0) = o;
    ushort4 ob; ob.x = f2bu(o.x); ob.y = f2bu(o.y); ob.z = f2bu(o.z); ob.w = f2bu(o.w);
    *reinterpret_cast<ushort4*>(hb0 + (size_t)row * KP + d0) = ob;
  } else if (d0 < KP) {
    ushort4 z; z.x = z.y = z.z = z.w = 0;
    *reinterpret_cast<ushort4*>(hb0 + (size_t)row * KP + d0) = z;
  }
}

DEVINL void inith0_body(int b, const float* er, float* h0) {
  int i = b * 256 + threadIdx.x;
  if (i < R2C * H) h0[i] = er[i];
}

DEVINL void relw_body(int b, const float* er, const float* wn, unsigned short* relWb) {
  __shared__ float a[H];
  int r = b;
  for (int d = threadIdx.x; d < H; d += 256) a[d] = er[r * H + d];
  __syncthreads();
  for (int c = threadIdx.x; c < H; c += 256) {
    float s = 0.f;
    for (int k = 0; k < H; k++) s += a[k] * wn[k * H + c];
    relWb[r * H + c] = f2bu(s);
  }
}

DEVINL void packb_body(int b, const float* wn, const float* tg, unsigned short* bpack) {
  int t = b * 256 + threadIdx.x;
  int total = 2 * NT * KS * 64;
  if (t >= total) return;
  int m    = t / (NT * KS * 64);
  int rem  = t % (NT * KS * 64);
  int nt   = rem / (KS * 64);
  int rem2 = rem % (KS * 64);
  int ks   = rem2 / 64, lane = rem2 % 64;
  const float* W = m ? tg : wn;
  int n = nt * 16 + (lane & 15);
  unsigned short out[8];
  #pragma unroll
  for (int j = 0; j < 8; j++) {
    int k = ks * 32 + (lane >> 4) * 8 + j;
    float v = (k < H && n < H) ? W[k * H + n] : 0.f;
    out[j] = f2bu(v);
  }
  unsigned short* dst = bpack + (size_t)t * 8;
  #pragma unroll
  for (int j = 0; j < 8; j++) dst[j] = out[j];
}

DEVINL void packgru_body(int b, const float* __restrict__ wih, const float* __restrict__ whh,
                         unsigned short* __restrict__ bgi, unsigned short* __restrict__ bgh) {
  int t = b * 256 + threadIdx.x;
  const int tot_i = GNT * GKI * 64;
  const int tot_h = GNT * GKH * 64;
  if (t < tot_i) {
    int nt = t / (GKI * 64);
    int rem = t % (GKI * 64);
    int ks = rem / 64, lane = rem % 64;
    int n = nt * 16 + (lane & 15);
    unsigned short o[8];
    #pragma unroll
    for (int j = 0; j < 8; j++) {
      int k = ks * 32 + (lane >> 4) * 8 + j;
      o[j] = (n < 3 * H && k < 2 * H) ? f2bu(wih[n * (2 * H) + k]) : (unsigned short)0;
    }
    unsigned short* dstp = bgi + (size_t)t * 8;
    #pragma unroll
    for (int j = 0; j < 8; j++) dstp[j] = o[j];
  } else if (t < tot_i + tot_h) {
    int t2 = t - tot_i;
    int nt = t2 / (GKH * 64);
    int rem = t2 % (GKH * 64);
    int ks = rem / 64, lane = rem % 64;
    int n = nt * 16 + (lane & 15);
    unsigned short o[8];
    #pragma unroll
    for (int j = 0; j < 8; j++) {
      int k = ks * 32 + (lane >> 4) * 8 + j;
      o[j] = (n < 3 * H && k < H) ? f2bu(whh[n * H + k]) : (unsigned short)0;
    }
    unsigned short* dstp = bgh + (size_t)t2 * 8;
    #pragma unroll
    for (int j = 0; j < 8; j++) dstp[j] = o[j];
  }
}

DEVINL void segb_body(int b, const int* __restrict__ rseg, int* __restrict__ segstart4) {
  const int* rs = rseg + (size_t)b * EC;
  int* out = segstart4 + b * (R2C + 1);
  for (int r = threadIdx.x; r <= R2C; r += 256) {
    int lo = 0, hi = EC;
    while (lo < hi) { int m = (lo + hi) >> 1; if (rs[m] < r) lo = m + 1; else hi = m; }
    out[r] = lo;
  }
}

// fused prologue: all independent setup work in one launch
__global__ __launch_bounds__(256) void k_prologue(const float* __restrict__ de,
                                                  float* __restrict__ h,
                                                  unsigned short* __restrict__ hb0,
                                                  const float* __restrict__ er,
                                                  float* __restrict__ h0,
                                                  const float* __restrict__ wn,
                                                  unsigned short* __restrict__ relWb,
                                                  const float* __restrict__ tg,
                                                  unsigned short* __restrict__ bpack,
                                                  const float* __restrict__ wih,
                                                  const float* __restrict__ whh,
                                                  unsigned short* __restrict__ bgi,
                                                  unsigned short* __restrict__ bgh,
                                                  const int* __restrict__ rseg,
                                                  int* __restrict__ segstart4,
                                                  float* __restrict__ sums4,
                                                  int* __restrict__ deg4) {
  int b = blockIdx.x;
  if (b < PO0)       inith_body(b, de, h, hb0);
  else if (b < PO1)  inith0_body(b - PO0, er, h0);
  else if (b < PO2)  relw_body(b - PO1, er, wn, relWb);
  else if (b < PO3)  packb_body(b - PO2, wn, tg, bpack);
  else if (b < PO4)  packgru_body(b - PO3, wih, whh, bgi, bgh);
  else if (b < PO5)  segb_body(b - PO4, rseg, segstart4);
  else if (b < PO6) { int i = (b - PO5) * 256 + threadIdx.x; if (i < TS * R2C * H) sums4[i] = 0.f; }
  else              { int i = (b - PO6) * 256 + threadIdx.x; if (i < TS * NE) deg4[i] = 0; }
}

// ================= CSR build (hist + scans) =================

__global__ void k_hist4(const int* __restrict__ dst, int* __restrict__ deg4) {
  int base = (blockIdx.x * 256 + threadIdx.x) * 4;
  if (base + 3 < TS * EC) {
    int4 d4 = *reinterpret_cast<const int4*>(dst + base);
    int t = base / EC;   // EC%4==0, base%4==0 -> whole quad in one step
    atomicAdd(&deg4[t * NE + d4.x], 1);
    atomicAdd(&deg4[t * NE + d4.y], 1);
    atomicAdd(&deg4[t * NE + d4.z], 1);
    atomicAdd(&deg4[t * NE + d4.w], 1);
  }
}

__global__ __launch_bounds__(256) void k_scan1(const int* __restrict__ deg4,
                                               int* __restrict__ offs4,
                                               int* __restrict__ bsums4) {
  __shared__ int s[256];
  int t = blockIdx.x / NSCAN, blk = blockIdx.x % NSCAN;
  int i = blk * 256 + threadIdx.x;
  int v = (i < NE) ? deg4[t * NE + i] : 0;
  s[threadIdx.x] = v;
  __syncthreads();
  for (int o = 1; o < 256; o <<= 1) {
    int add = (threadIdx.x >= o) ? s[threadIdx.x - o] : 0;
    __syncthreads();
    s[threadIdx.x] += add;
    __syncthreads();
  }
  if (i < NE) offs4[t * (NE + 1) + i] = s[threadIdx.x] - v;  // exclusive
  if (threadIdx.x == 255) bsums4[t * 256 + blk] = s[255];
}

__global__ __launch_bounds__(256) void k_scan2(int* bsums4) {
  __shared__ int s[256];
  int t = blockIdx.x;
  int v = (threadIdx.x < NSCAN) ? bsums4[t * 256 + threadIdx.x] : 0;
  s[threadIdx.x] = v;
  __syncthreads();
  for (int o = 1; o < 256; o <<= 1) {
    int add = (threadIdx.x >= o) ? s[threadIdx.x - o] : 0;
    __syncthreads();
    s[threadIdx.x] += add;
    __syncthreads();
  }
  if (threadIdx.x < NSCAN) bsums4[t * 256 + threadIdx.x] = s[threadIdx.x] - v;  // exclusive
}

__global__ void k_scan3(int* __restrict__ offs4, const int* __restrict__ bsums4,
                        int* __restrict__ cursor4) {
  int t = blockIdx.x / NSCAN, blk = blockIdx.x % NSCAN;
  int i = blk * 256 + threadIdx.x;
  if (i < NE) {
    int o = offs4[t * (NE + 1) + i] + bsums4[t * 256 + blk];
    offs4[t * (NE + 1) + i] = o;
    cursor4[t * NE + i] = o;
  }
  if (blk == 0 && threadIdx.x == 0) offs4[t * (NE + 1) + NE] = EC;
}

// ================= device bodies for fused per-step kernels =================

// dst-range-partitioned scatter for ONE step t (XCD-local writes), block id = b
DEVINL void scatter_body(int b, int t, const int* __restrict__ dst, const int* __restrict__ src,
                         const int* __restrict__ et, int* __restrict__ cursor4,
                         unsigned int* __restrict__ se4) {
  int r = b & (NRNG - 1);
  int chunk = b >> 3;
  int li = chunk * SCHK + threadIdx.x * 4;
  if (li >= EC) return;                     // EC%4==0 so full quad when li<EC
  int base = t * EC + li;
  int4 d4 = *reinterpret_cast<const int4*>(dst + base);
  int4 s4 = *reinterpret_cast<const int4*>(src + base);
  int4 e4 = *reinterpret_cast<const int4*>(et + base);
  int* cur = cursor4 + t * NE;
  unsigned int* se = se4 + (size_t)t * EC;
  if ((unsigned)d4.x / DRNG == (unsigned)r) {
    int p = atomicAdd(&cur[d4.x], 1);
    se[p] = (unsigned int)s4.x | ((unsigned int)e4.x << 16);
  }
  if ((unsigned)d4.y / DRNG == (unsigned)r) {
    int p = atomicAdd(&cur[d4.y], 1);
    se[p] = (unsigned int)s4.y | ((unsigned int)e4.y << 16);
  }
  if ((unsigned)d4.z / DRNG == (unsigned)r) {
    int p = atomicAdd(&cur[d4.z], 1);
    se[p] = (unsigned int)s4.z | ((unsigned int)e4.z << 16);
  }
  if ((unsigned)d4.w / DRNG == (unsigned)r) {
    int p = atomicAdd(&cur[d4.w], 1);
    se[p] = (unsigned int)s4.w | ((unsigned int)e4.w << 16);
  }
}

// segment-sum over sorted rseg, block id = b
DEVINL void relsums_body(int b, const int* __restrict__ rseg, const int* __restrict__ rte,
                         const unsigned short* __restrict__ hb, float* __restrict__ sums) {
  int base = b * RCH;
  int d = threadIdx.x;
  bool act = d < H;
  float a0 = 0.f, a1 = 0.f, a2 = 0.f, a3 = 0.f;
  int prev = rseg[base];
  for (int g = 0; g < RCH; g += 8) {
    int e = base + g;
    int4 sgA = *reinterpret_cast<const int4*>(rseg + e);
    int4 sgB = *reinterpret_cast<const int4*>(rseg + e + 4);
    int4 rrA = *reinterpret_cast<const int4*>(rte + e);
    int4 rrB = *reinterpret_cast<const int4*>(rte + e + 4);
    if (sgB.w == prev) {           // sorted => whole group of 8 in same segment
      if (act) {
        float v0 = u2f(hb[(size_t)rrA.x * KP + d]);
        float v1 = u2f(hb[(size_t)rrA.y * KP + d]);
        float v2 = u2f(hb[(size_t)rrA.z * KP + d]);
        float v3 = u2f(hb[(size_t)rrA.w * KP + d]);
        float v4 = u2f(hb[(size_t)rrB.x * KP + d]);
        float v5 = u2f(hb[(size_t)rrB.y * KP + d]);
        float v6 = u2f(hb[(size_t)rrB.z * KP + d]);
        float v7 = u2f(hb[(size_t)rrB.w * KP + d]);
        a0 += v0; a1 += v1; a2 += v2; a3 += v3;
        a0 += v4; a1 += v5; a2 += v6; a3 += v7;
      }
    } else {                       // boundary group (rare): scalar path
      int ss[8] = {sgA.x, sgA.y, sgA.z, sgA.w, sgB.x, sgB.y, sgB.z, sgB.w};
      int rr[8] = {rrA.x, rrA.y, rrA.z, rrA.w, rrB.x, rrB.y, rrB.z, rrB.w};
      #pragma unroll
      for (int j = 0; j < 8; j++) {
        if (ss[j] != prev) {
          if (act) atomicAdd(&sums[prev * H + d], a0 + a1 + a2 + a3);
          a0 = a1 = a2 = a3 = 0.f;
          prev = ss[j];
        }
        if (act) a0 += u2f(hb[(size_t)rr[j] * KP + d]);
      }
    }
  }
  if (act) atomicAdd(&sums[prev * H + d], a0 + a1 + a2 + a3);
}

// node GEMMs via MFMA, block id = b
DEVINL void gemm_body(int b, const unsigned short* __restrict__ hb,
                      const unsigned short* __restrict__ bpack,
                      const float* __restrict__ tgb,
                      bf16* __restrict__ hWb, bf16* __restrict__ twb) {
  int wid = threadIdx.x >> 6, lane = threadIdx.x & 63;
  int row0 = b * 64 + wid * 16;
  if (row0 >= NE) return;                 // wave-uniform
  int arow = min(row0 + (lane & 15), NE - 1);
  const unsigned short* ap = hb + (size_t)arow * KP + (lane >> 4) * 8;
  bf16x8v a[KS];
  #pragma unroll
  for (int ks = 0; ks < KS; ks++)
    a[ks] = *reinterpret_cast<const bf16x8v*>(ap + ks * 32);

  const unsigned short* b1p = bpack + (size_t)lane * 8;
  const unsigned short* b2p = b1p + (size_t)NT * KS * 64 * 8;
  int colb = lane & 15;
  int rbase = row0 + (lane >> 4) * 4;

  for (int nt = 0; nt < NT; nt++) {
    bf16x8v b1[KS], b2[KS];
    #pragma unroll
    for (int ks = 0; ks < KS; ks++) {
      size_t boff = (size_t)(nt * KS + ks) * 64 * 8;
      b1[ks] = *reinterpret_cast<const bf16x8v*>(b1p + boff);
      b2[ks] = *reinterpret_cast<const bf16x8v*>(b2p + boff);
    }
    f32x4 acc1 = {}, acc2 = {};
    #pragma unroll
    for (int ks = 0; ks < KS; ks++) {
      acc1 = __builtin_amdgcn_mfma_f32_16x16x32_bf16(a[ks], b1[ks], acc1, 0, 0, 0);
      acc2 = __builtin_amdgcn_mfma_f32_16x16x32_bf16(a[ks], b2[ks], acc2, 0, 0, 0);
    }
    int col = nt * 16 + colb;
    bool cok = (col < H);
    float bias = cok ? tgb[col] : 0.f;
    #pragma unroll
    for (int q = 0; q < 4; q++) {
      int row = rbase + q;
      if (cok && row < NE) {
        hWb[(size_t)row * H + col] = f2b(acc1[q]);
        twb[(size_t)row * H + col] = f2b(sigmoidf(acc2[q] + bias));
      }
    }
  }
}

// aggregate + rrelu + l2norm + time gate + l2norm (+ hbnext emit), block id = b
DEVINL void aggfin_body(int b, const int* __restrict__ offs,
                        const unsigned int* __restrict__ se,
                        const bf16* __restrict__ hWb,
                        const unsigned short* __restrict__ relWb,
                        const bf16* __restrict__ twb,
                        float* __restrict__ h, float* __restrict__ evolve,
                        unsigned short* __restrict__ hbnext) {
  int wid = threadIdx.x >> 6, lane = threadIdx.x & 63;
  int i = b * 4 + wid;
  if (i >= NE) return;
  int s0 = offs[i], s1 = offs[i + 1];
  int d0 = lane * 4;
  bool act = d0 < H;
  const unsigned short* hw = (const unsigned short*)hWb;
  float a0 = 0.f, a1 = 0.f, a2 = 0.f, a3 = 0.f;

  int p = s0;
  for (; p + 4 <= s1; p += 4) {
    unsigned int e0 = se[p], e1 = se[p + 1], e2 = se[p + 2], e3 = se[p + 3];
    if (act) {
      ushort4 m0 = *reinterpret_cast<const ushort4*>(hw + (size_t)(e0 & 0xFFFFu) * H + d0);
      ushort4 m1 = *reinterpret_cast<const ushort4*>(hw + (size_t)(e1 & 0xFFFFu) * H + d0);
      ushort4 m2 = *reinterpret_cast<const ushort4*>(hw + (size_t)(e2 & 0xFFFFu) * H + d0);
      ushort4 m3 = *reinterpret_cast<const ushort4*>(hw + (size_t)(e3 & 0xFFFFu) * H + d0);
      ushort4 r0 = *reinterpret_cast<const ushort4*>(relWb + (size_t)(e0 >> 16) * H + d0);
      ushort4 r1 = *reinterpret_cast<const ushort4*>(relWb + (size_t)(e1 >> 16) * H + d0);
      ushort4 r2 = *reinterpret_cast<const ushort4*>(relWb + (size_t)(e2 >> 16) * H + d0);
      ushort4 r3 = *reinterpret_cast<const ushort4*>(relWb + (size_t)(e3 >> 16) * H + d0);
      a0 += u2f(m0.x) + u2f(r0.x) + u2f(m1.x) + u2f(r1.x)
          + u2f(m2.x) + u2f(r2.x) + u2f(m3.x) + u2f(r3.x);
      a1 += u2f(m0.y) + u2f(r0.y) + u2f(m1.y) + u2f(r1.y)
          + u2f(m2.y) + u2f(r2.y) + u2f(m3.y) + u2f(r3.y);
      a2 += u2f(m0.z) + u2f(r0.z) + u2f(m1.z) + u2f(r1.z)
          + u2f(m2.z) + u2f(r2.z) + u2f(m3.z) + u2f(r3.z);
      a3 += u2f(m0.w) + u2f(r0.w) + u2f(m1.w) + u2f(r1.w)
          + u2f(m2.w) + u2f(r2.w) + u2f(m3.w) + u2f(r3.w);
    }
  }
  for (; p < s1; p++) {
    unsigned int e0 = se[p];
    if (act) {
      ushort4 m0 = *reinterpret_cast<const ushort4*>(hw + (size_t)(e0 & 0xFFFFu) * H + d0);
      ushort4 r0 = *reinterpret_cast<const ushort4*>(relWb + (size_t)(e0 >> 16) * H + d0);
      a0 += u2f(m0.x) + u2f(r0.x);
      a1 += u2f(m0.y) + u2f(r0.y);
      a2 += u2f(m0.z) + u2f(r0.z);
      a3 += u2f(m0.w) + u2f(r0.w);
    }
  }

  int deg = s1 - s0;
  float nrm = deg > 0 ? 1.0f / (float)deg : 0.0f;
  float c0 = a0 * nrm; c0 = c0 >= 0.f ? c0 : SLOPE * c0;
  float c1 = a1 * nrm; c1 = c1 >= 0.f ? c1 : SLOPE * c1;
  float c2 = a2 * nrm; c2 = c2 >= 0.f ? c2 : SLOPE * c2;
  float c3 = a3 * nrm; c3 = c3 >= 0.f ? c3 : SLOPE * c3;
  float ss = act ? (c0 * c0 + c1 * c1 + c2 * c2 + c3 * c3) : 0.f;
  ss = wave_sum(ss);
  float sc = 1.0f / fmaxf(sqrtf(ss), 1e-12f);
  c0 *= sc; c1 *= sc; c2 *= sc; c3 *= sc;

  // time gate + combine + l2norm
  float v0 = 0.f, v1 = 0.f, v2 = 0.f, v3 = 0.f;
  if (act) {
    ushort4 t4 = *reinterpret_cast<const ushort4*>((const unsigned short*)twb + (size_t)i * H + d0);
    float4 hv = *reinterpret_cast<const float4*>(h + (size_t)i * H + d0);
    float t0 = u2f(t4.x), t1 = u2f(t4.y), t2 = u2f(t4.z), t3 = u2f(t4.w);
    v0 = t0 * c0 + (1.0f - t0) * hv.x;
    v1 = t1 * c1 + (1.0f - t1) * hv.y;
    v2 = t2 * c2 + (1.0f - t2) * hv.z;
    v3 = t3 * c3 + (1.0f - t3) * hv.w;
  }
  float ss2 = v0 * v0 + v1 * v1 + v2 * v2 + v3 * v3;
  ss2 = wave_sum(ss2);
  float sc2 = 1.0f / fmaxf(sqrtf(ss2), 1e-12f);
  if (act) {
    float4 o = make_float4(v0 * sc2, v1 * sc2, v2 * sc2, v3 * sc2);
    *reinterpret_cast<float4*>(h + (size_t)i * H + d0) = o;
    *reinterpret_cast<float4*>(evolve + (size_t)i * H + d0) = o;
    if (hbnext) {
      ushort4 ob; ob.x = f2bu(o.x); ob.y = f2bu(o.y); ob.z = f2bu(o.z); ob.w = f2bu(o.w);
      *reinterpret_cast<ushort4*>(hbnext + (size_t)i * KP + d0) = ob;
    }
  } else if (d0 < KP && hbnext) {
    ushort4 z; z.x = z.y = z.z = z.w = 0;
    *reinterpret_cast<ushort4*>(hbnext + (size_t)i * KP + d0) = z;
  }
}

// GRU A-matrix build, block id = b
DEVINL void a2b_body(int b, const float* __restrict__ er, const float* __restrict__ sums,
                     const int* __restrict__ segstart, const float* __restrict__ h0,
                     unsigned short* __restrict__ xcatb, unsigned short* __restrict__ h0b) {
  int i = b * 256 + threadIdx.x;
  const int n1 = GR * 416;
  if (i < n1) {
    int r = i / 416, c = i % 416;
    float v = 0.f;
    if (r < R2C) {
      if (c < H) v = er[r * H + c];
      else if (c < 2 * H) {
        int cnt = segstart[r + 1] - segstart[r];
        float inv = cnt > 0 ? 1.0f / (float)cnt : 0.0f;
        v = sums[r * H + (c - H)] * inv;
      }
    }
    xcatb[i] = f2bu(v);
  } else {
    int i2 = i - n1;
    if (i2 < GR * 224) {
      int r = i2 / 224, c = i2 % 224;
      float v = (r < R2C && c < H) ? h0[r * H + c] : 0.f;
      h0b[i2] = f2bu(v);
    }
  }
}

// ---------------- fused: node GEMM + relsums + this step's CSR scatter ----------------
__global__ __launch_bounds__(256) void k_rsgemm(int t,
                                                const int* __restrict__ rseg,
                                                const int* __restrict__ rte,
                                                const unsigned short* __restrict__ hb,
                                                float* __restrict__ sums,
                                                const unsigned short* __restrict__ bpack,
                                                const float* __restrict__ tgb,
                                                bf16* __restrict__ hWb,
                                                bf16* __restrict__ twb,
                                                const int* __restrict__ dst,
                                                const int* __restrict__ src,
                                                const int* __restrict__ et,
                                                int* __restrict__ cursor4,
                                                unsigned int* __restrict__ se4) {
  int b = blockIdx.x;
  if (b < GB_GEMM)
    gemm_body(b, hb, bpack, tgb, hWb, twb);
  else if (b < GB_GEMM + GB_RELS)
    relsums_body(b - GB_GEMM, rseg, rte, hb, sums);
  else
    scatter_body(b - (GB_GEMM + GB_RELS), t, dst, src, et, cursor4, se4);
}

// ---------------- fused: aggfin (blocks 0..12499) + a2b (rest) ----------------
__global__ __launch_bounds__(256) void k_afa2b(const int* __restrict__ offs,
                                               const unsigned int* __restrict__ se,
                                               const bf16* __restrict__ hWb,
                                               const unsigned short* __restrict__ relWb,
                                               const bf16* __restrict__ twb,
                                               float* __restrict__ h,
                                               float* __restrict__ evolve,
                                               unsigned short* __restrict__ hbnext,
                                               const float* __restrict__ er,
                                               const float* __restrict__ sums,
                                               const int* __restrict__ segstart,
                                               const float* __restrict__ h0,
                                               unsigned short* __restrict__ xcatb,
                                               unsigned short* __restrict__ h0b) {
  if (blockIdx.x < GB_AGG)
    aggfin_body(blockIdx.x, offs, se, hWb, relWb, twb, h, evolve, hbnext);
  else
    a2b_body(blockIdx.x - GB_AGG, er, sums, segstart, h0, xcatb, h0b);
}

// ---------------- per-step: GRU GEMMs via MFMA -> gi, gh [512][608] f32 ----------------
__global__ __launch_bounds__(256) void k_grumm(const unsigned short* __restrict__ xcatb,
                                               const unsigned short* __restrict__ h0b,
                                               const unsigned short* __restrict__ bgi,
                                               const unsigned short* __restrict__ bgh,
                                               float* __restrict__ gi_ws,
                                               float* __restrict__ gh_ws) {
  int wid = threadIdx.x >> 6, lane = threadIdx.x & 63;
  int nt   = blockIdx.x % GNT;
  int row0 = (blockIdx.x / GNT) * 64 + wid * 16;
  int arow = row0 + (lane & 15);

  const unsigned short* api = xcatb + (size_t)arow * 416 + (lane >> 4) * 8;
  bf16x8v ai[GKI];
  #pragma unroll
  for (int ks = 0; ks < GKI; ks++)
    ai[ks] = *reinterpret_cast<const bf16x8v*>(api + ks * 32);
  const unsigned short* aph = h0b + (size_t)arow * 224 + (lane >> 4) * 8;
  bf16x8v ah[GKH];
  #pragma unroll
  for (int ks = 0; ks < GKH; ks++)
    ah[ks] = *reinterpret_cast<const bf16x8v*>(aph + ks * 32);

  const unsigned short* bip = bgi + ((size_t)(nt * GKI) * 64 + lane) * 8;
  bf16x8v bi[GKI];
  #pragma unroll
  for (int ks = 0; ks < GKI; ks++)
    bi[ks] = *reinterpret_cast<const bf16x8v*>(bip + (size_t)ks * 64 * 8);
  const unsigned short* bhp = bgh + ((size_t)(nt * GKH) * 64 + lane) * 8;
  bf16x8v bh[GKH];
  #pragma unroll
  for (int ks = 0; ks < GKH; ks++)
    bh[ks] = *reinterpret_cast<const bf16x8v*>(bhp + (size_t)ks * 64 * 8);

  f32x4 a1 = {}, a2 = {};
  #pragma unroll
  for (int ks = 0; ks < GKI; ks++)
    a1 = __builtin_amdgcn_mfma_f32_16x16x32_bf16(ai[ks], bi[ks], a1, 0, 0, 0);
  #pragma unroll
  for (int ks = 0; ks < GKH; ks++)
    a2 = __builtin_amdgcn_mfma_f32_16x16x32_bf16(ah[ks], bh[ks], a2, 0, 0, 0);

  int col = nt * 16 + (lane & 15);
  int rb = row0 + (lane >> 4) * 4;
  #pragma unroll
  for (int q = 0; q < 4; q++) {
    gi_ws[(size_t)(rb + q) * GCS + col] = a1[q];
    gh_ws[(size_t)(rb + q) * GCS + col] = a2[q];
  }
}

// ---------------- per-step: GRU gates + l2norm -> h0 (and h0_out on last step) ----------------
__global__ __launch_bounds__(256) void k_grutail(const float* __restrict__ gi_ws,
                                                 const float* __restrict__ gh_ws,
                                                 const float* __restrict__ b_ih,
                                                 const float* __restrict__ b_hh,
                                                 float* __restrict__ h0,
                                                 float* __restrict__ h0_out) {
  __shared__ float xc[H];
  __shared__ float red[4];
  int r = blockIdx.x;
  int tid = threadIdx.x, wid = tid >> 6, lane = tid & 63;
  float ssp = 0.f;
  for (int d = tid; d < H; d += 256) {
    float gir = gi_ws[(size_t)r * GCS + d]         + b_ih[d];
    float ghr = gh_ws[(size_t)r * GCS + d]         + b_hh[d];
    float giz = gi_ws[(size_t)r * GCS + H + d]     + b_ih[H + d];
    float ghz = gh_ws[(size_t)r * GCS + H + d]     + b_hh[H + d];
    float gin = gi_ws[(size_t)r * GCS + 2 * H + d] + b_ih[2 * H + d];
    float ghn = gh_ws[(size_t)r * GCS + 2 * H + d] + b_hh[2 * H + d];
    float rg = sigmoidf(gir + ghr);
    float z  = sigmoidf(giz + ghz);
    float n  = tanhf(gin + rg * ghn);
    float hv = h0[r * H + d];
    float o  = (1.0f - z) * n + z * hv;
    xc[d] = o;
    ssp += o * o;
  }
  ssp = wave_sum(ssp);
  if (lane == 0) red[wid] = ssp;
  __syncthreads();
  float ss = red[0] + red[1] + red[2] + red[3];
  float sc = 1.0f / fmaxf(sqrtf(ss), 1e-12f);
  for (int d = tid; d < H; d += 256) {
    float o = xc[d] * sc;
    h0[r * H + d] = o;
    if (h0_out) h0_out[r * H + d] = o;
  }
}

extern "C" void kernel_launch(void* const* d_in, const int* in_sizes, int n_in,
                              void* d_out, int out_size, void* d_ws, size_t ws_size,
                              hipStream_t stream) {
  const float* de  = (const float*)d_in[0];
  const float* er  = (const float*)d_in[1];
  const float* wih = (const float*)d_in[2];
  const float* whh = (const float*)d_in[3];
  const float* bih = (const float*)d_in[4];
  const float* bhh = (const float*)d_in[5];
  const float* wn  = (const float*)d_in[6];
  const float* tg  = (const float*)d_in[7];
  const float* tgb = (const float*)d_in[8];
  const int* src  = (const int*)d_in[9];
  const int* dst  = (const int*)d_in[10];
  const int* et   = (const int*)d_in[11];
  const int* rte  = (const int*)d_in[12];
  const int* rseg = (const int*)d_in[13];

  char* w = (char*)d_ws;
  auto alloc = [&](size_t bytes) -> char* {
    char* p = w;
    w += (bytes + 255) / 256 * 256;
    return p;
  };
  float* h     = (float*)alloc(sizeof(float) * (size_t)NE * H);   // 40 MB
  bf16*  hWb   = (bf16*) alloc(sizeof(bf16)  * (size_t)NE * H);   // 20 MB
  bf16*  twb   = (bf16*) alloc(sizeof(bf16)  * (size_t)NE * H);   // 20 MB
  unsigned short* relWb = (unsigned short*)alloc(sizeof(unsigned short) * R2C * H); // 200 KB
  float* h0    = (float*)alloc(sizeof(float) * R2C * H);
  float* sums4 = (float*)alloc(sizeof(float) * TS * R2C * H);     // 1.6 MB
  unsigned short* bpack = (unsigned short*)alloc(sizeof(unsigned short) * 2 * NT * KS * 64 * 8); // 186 KB
  unsigned short* bgi   = (unsigned short*)alloc(sizeof(unsigned short) * GNT * GKI * 64 * 8);   // 506 KB
  unsigned short* bgh   = (unsigned short*)alloc(sizeof(unsigned short) * GNT * GKH * 64 * 8);   // 272 KB
  unsigned short* xcatb = (unsigned short*)alloc(sizeof(unsigned short) * GR * 416);             // 416 KB
  unsigned short* h0b   = (unsigned short*)alloc(sizeof(unsigned short) * GR * 224);             // 224 KB
  float* gi_ws = (float*)alloc(sizeof(float) * GR * GCS);          // 1.24 MB
  float* gh_ws = (float*)alloc(sizeof(float) * GR * GCS);          // 1.24 MB
  int* segstart4 = (int*)alloc(sizeof(int) * TS * (R2C + 1));
  int* deg4    = (int*) alloc(sizeof(int) * TS * NE);              // 800 KB
  int* offs4   = (int*) alloc(sizeof(int) * TS * (NE + 1));        // 800 KB
  int* cursor4 = (int*) alloc(sizeof(int) * TS * NE);              // 800 KB
  unsigned int* se4 = (unsigned int*)alloc(sizeof(unsigned int) * (size_t)TS * EC); // 6.4 MB
  int* bsums4  = (int*) alloc(sizeof(int) * TS * 256);
  (void)ws_size; (void)in_sizes; (void)n_in; (void)out_size;

  float* out    = (float*)d_out;
  float* evolve = out;                       // [TS, NE, H]
  float* h0out  = out + (size_t)TS * NE * H; // [R2C, H]

  const int gGru   = 8 * GNT;                              // 304
  const int gE4i   = (TS * EC / 4 + 255) / 256;            // 1563

  // ---- prologue: fused setup + CSR scan chain ----
  k_prologue<<<PO7, 256, 0, stream>>>(de, h, (unsigned short*)evolve, er, h0,
                                      wn, relWb, tg, bpack, wih, whh, bgi, bgh,
                                      rseg, segstart4, sums4, deg4);
  k_hist4<<<gE4i, 256, 0, stream>>>(dst, deg4);
  k_scan1<<<TS * NSCAN, 256, 0, stream>>>(deg4, offs4, bsums4);
  k_scan2<<<TS, 256, 0, stream>>>(bsums4);
  k_scan3<<<TS * NSCAN, 256, 0, stream>>>(offs4, bsums4, cursor4);

  for (int t = 0; t < TS; t++) {
    const int* rseg_t = rseg + (size_t)t * EC;
    const int* rte_t  = rte  + (size_t)t * EC;
    float* sums_t = sums4 + (size_t)t * R2C * H;
    float* evo_t = evolve + (size_t)t * NE * H;
    // hb(t) lives in the evolve[t] slot (written by init_h body for t=0, else by
    // the previous step's aggfin); it is dead before aggfin overwrites it.
    unsigned short* hb = (unsigned short*)evo_t;
    unsigned short* hbnext = (t < TS - 1) ? (unsigned short*)(evolve + (size_t)(t + 1) * NE * H)
                                          : (unsigned short*)nullptr;

    // fused: node GEMM (MFMA) ∥ relation-segment sums ∥ step t's CSR scatter
    k_rsgemm<<<GB_GEMM + GB_RELS + GSCAT1, 256, 0, stream>>>(
        t, rseg_t, rte_t, hb, sums_t, bpack, tgb, hWb, twb,
        dst, src, et, cursor4, se4);

    // fused: aggregate+timegate (writes h, evolve[t], hbnext) ∥ GRU A-matrix build
    k_afa2b<<<GB_AGG + GB_A2B, 256, 0, stream>>>(offs4 + t * (NE + 1), se4 + (size_t)t * EC,
                                                 hWb, relWb, twb, h, evo_t, hbnext,
                                                 er, sums_t, segstart4 + t * (R2C + 1),
                                                 h0, xcatb, h0b);

    // GRU GEMMs + gates (updates h0; h0_out on last step)
    k_grumm<<<gGru, 256, 0, stream>>>(xcatb, h0b, bgi, bgh, gi_ws, gh_ws);
    k_grutail<<<R2C, 256, 0, stream>>>(gi_ws, gh_ws, bih, bhh,
                                       h0, (t == TS - 1) ? h0out : (float*)nullptr);
  }
}

// Round 19
// 638.160 us; speedup vs baseline: 1.1565x; 1.0570x over previous
//
#include <hip/hip_runtime.h>
#include <hip/hip_bf16.h>

using bf16 = __hip_bfloat16;

constexpr int NE  = 50000;   // entities
constexpr int H   = 200;     // hidden dim
constexpr int R2C = 500;     // 2*num_rels
constexpr int TS  = 4;       // timesteps
constexpr int EC  = 400000;  // edges per step
constexpr float SLOPE = 0.22916666666666666f;  // rrelu eval slope
constexpr int NSCAN = (NE + 255) / 256;        // 196

// node-GEMM MFMA geometry
constexpr int KP = 224;      // K padded to 7*32
constexpr int KS = 7;        // k-steps of 32
constexpr int NT = 13;       // n-tiles of 16

// GRU-GEMM MFMA geometry (out [512][608])
constexpr int GNT = 38;      // n-tiles (608/16)
constexpr int GKI = 13;      // k-steps for W_ih (416/32)
constexpr int GKH = 7;       // k-steps for W_hh (224/32)
constexpr int GR  = 512;     // padded relation rows
constexpr int GCS = 608;     // padded gate cols (stride)

constexpr int RCH = 64;      // edges per block in relsums part
constexpr int NRNG = 8;      // dst ranges (≈ XCD count); NE/NRNG = 6250
constexpr int DRNG = NE / NRNG;              // 6250
constexpr int SCHK = 1024;   // edges per scatter chunk
constexpr int NCHK = (EC + SCHK - 1) / SCHK; // 391
constexpr int GSCAT1 = NCHK * NRNG;          // 3128 (one step's scatter blocks)

// fused-kernel block counts
constexpr int GB_GEMM  = (NE + 63) / 64;     // 782
constexpr int GB_RELS  = EC / RCH;           // 6250
constexpr int GB_AGG   = (NE + 3) / 4;       // 12500
constexpr int GB_A2B   = (GR * 416 + GR * 224 + 255) / 256; // 1280

// prologue block layout
constexpr int PB_INITH  = (NE + 3) / 4;                       // 12500
constexpr int PB_INITH0 = (R2C * H + 255) / 256;              // 391
constexpr int PB_RELW   = R2C;                                // 500
constexpr int PB_PACKB  = (2 * NT * KS * 64 + 255) / 256;     // 46
constexpr int PB_PACKG  = (GNT * (GKI + GKH) * 64 + 255) / 256; // 190
constexpr int PB_SEGB   = TS;                                 // 4
constexpr int PB_ZS     = (TS * R2C * H + 255) / 256;         // 1563
constexpr int PB_ZI     = (TS * NE + 255) / 256;              // 782
constexpr int PO0 = PB_INITH;
constexpr int PO1 = PO0 + PB_INITH0;
constexpr int PO2 = PO1 + PB_RELW;
constexpr int PO3 = PO2 + PB_PACKB;
constexpr int PO4 = PO3 + PB_PACKG;
constexpr int PO5 = PO4 + PB_SEGB;
constexpr int PO6 = PO5 + PB_ZS;
constexpr int PO7 = PO6 + PB_ZI;   // total prologue blocks = 15976

#define DEVINL __device__ __forceinline__

typedef __bf16 bf16x8v __attribute__((ext_vector_type(8)));
typedef float  f32x4   __attribute__((ext_vector_type(4)));

DEVINL float b2f(bf16 v) { return __bfloat162float(v); }
DEVINL bf16  f2b(float v) { return __float2bfloat16(v); }
DEVINL unsigned short f2bu(float x) { bf16 b = f2b(x); return *reinterpret_cast<unsigned short*>(&b); }
DEVINL float u2f(unsigned short u) { unsigned int w = (unsigned int)u << 16; float f; __builtin_memcpy(&f, &w, 4); return f; }

DEVINL float wave_sum(float v) {
  #pragma unroll
  for (int o = 32; o > 0; o >>= 1) v += __shfl_xor(v, o, 64);
  return v;
}

DEVINL float sigmoidf(float x) { return 1.0f / (1.0f + expf(-x)); }

// ================= prologue bodies =================

// l2norm rows of dynamic_emb -> hb0 (bf16 padded); f32 h array is eliminated —
// state lives only as bf16 (the time-gate read tolerates bf16 quantization).
DEVINL void inith_body(int b, const float* __restrict__ de,
                       unsigned short* __restrict__ hb0) {
  int wid = threadIdx.x >> 6, lane = threadIdx.x & 63;
  int row = b * 4 + wid;
  if (row >= NE) return;
  int d0 = lane * 4;
  bool act = d0 < H;
  float4 v = make_float4(0.f, 0.f, 0.f, 0.f);
  if (act) v = *reinterpret_cast<const float4*>(de + (size_t)row * H + d0);
  float ss = v.x * v.x + v.y * v.y + v.z * v.z + v.w * v.w;
  ss = wave_sum(ss);
  float sc = 1.0f / fmaxf(sqrtf(ss), 1e-12f);
  if (d0 < KP) {
    ushort4 ob;
    if (act) {
      ob.x = f2bu(v.x * sc); ob.y = f2bu(v.y * sc);
      ob.z = f2bu(v.z * sc); ob.w = f2bu(v.w * sc);
    } else {
      ob.x = ob.y = ob.z = ob.w = 0;
    }
    *reinterpret_cast<ushort4*>(hb0 + (size_t)row * KP + d0) = ob;
  }
}

DEVINL void inith0_body(int b, const float* er, float* h0) {
  int i = b * 256 + threadIdx.x;
  if (i < R2C * H) h0[i] = er[i];
}

DEVINL void relw_body(int b, const float* er, const float* wn, unsigned short* relWb) {
  __shared__ float a[H];
  int r = b;
  for (int d = threadIdx.x; d < H; d += 256) a[d] = er[r * H + d];
  __syncthreads();
  for (int c = threadIdx.x; c < H; c += 256) {
    float s = 0.f;
    for (int k = 0; k < H; k++) s += a[k] * wn[k * H + c];
    relWb[r * H + c] = f2bu(s);
  }
}

DEVINL void packb_body(int b, const float* wn, const float* tg, unsigned short* bpack) {
  int t = b * 256 + threadIdx.x;
  int total = 2 * NT * KS * 64;
  if (t >= total) return;
  int m    = t / (NT * KS * 64);
  int rem  = t % (NT * KS * 64);
  int nt   = rem / (KS * 64);
  int rem2 = rem % (KS * 64);
  int ks   = rem2 / 64, lane = rem2 % 64;
  const float* W = m ? tg : wn;
  int n = nt * 16 + (lane & 15);
  unsigned short out[8];
  #pragma unroll
  for (int j = 0; j < 8; j++) {
    int k = ks * 32 + (lane >> 4) * 8 + j;
    float v = (k < H && n < H) ? W[k * H + n] : 0.f;
    out[j] = f2bu(v);
  }
  unsigned short* dst = bpack + (size_t)t * 8;
  #pragma unroll
  for (int j = 0; j < 8; j++) dst[j] = out[j];
}

DEVINL void packgru_body(int b, const float* __restrict__ wih, const float* __restrict__ whh,
                         unsigned short* __restrict__ bgi, unsigned short* __restrict__ bgh) {
  int t = b * 256 + threadIdx.x;
  const int tot_i = GNT * GKI * 64;
  const int tot_h = GNT * GKH * 64;
  if (t < tot_i) {
    int nt = t / (GKI * 64);
    int rem = t % (GKI * 64);
    int ks = rem / 64, lane = rem % 64;
    int n = nt * 16 + (lane & 15);
    unsigned short o[8];
    #pragma unroll
    for (int j = 0; j < 8; j++) {
      int k = ks * 32 + (lane >> 4) * 8 + j;
      o[j] = (n < 3 * H && k < 2 * H) ? f2bu(wih[n * (2 * H) + k]) : (unsigned short)0;
    }
    unsigned short* dstp = bgi + (size_t)t * 8;
    #pragma unroll
    for (int j = 0; j < 8; j++) dstp[j] = o[j];
  } else if (t < tot_i + tot_h) {
    int t2 = t - tot_i;
    int nt = t2 / (GKH * 64);
    int rem = t2 % (GKH * 64);
    int ks = rem / 64, lane = rem % 64;
    int n = nt * 16 + (lane & 15);
    unsigned short o[8];
    #pragma unroll
    for (int j = 0; j < 8; j++) {
      int k = ks * 32 + (lane >> 4) * 8 + j;
      o[j] = (n < 3 * H && k < H) ? f2bu(whh[n * H + k]) : (unsigned short)0;
    }
    unsigned short* dstp = bgh + (size_t)t2 * 8;
    #pragma unroll
    for (int j = 0; j < 8; j++) dstp[j] = o[j];
  }
}

DEVINL void segb_body(int b, const int* __restrict__ rseg, int* __restrict__ segstart4) {
  const int* rs = rseg + (size_t)b * EC;
  int* out = segstart4 + b * (R2C + 1);
  for (int r = threadIdx.x; r <= R2C; r += 256) {
    int lo = 0, hi = EC;
    while (lo < hi) { int m = (lo + hi) >> 1; if (rs[m] < r) lo = m + 1; else hi = m; }
    out[r] = lo;
  }
}

// fused prologue: all independent setup work in one launch
__global__ __launch_bounds__(256) void k_prologue(const float* __restrict__ de,
                                                  unsigned short* __restrict__ hb0,
                                                  const float* __restrict__ er,
                                                  float* __restrict__ h0,
                                                  const float* __restrict__ wn,
                                                  unsigned short* __restrict__ relWb,
                                                  const float* __restrict__ tg,
                                                  unsigned short* __restrict__ bpack,
                                                  const float* __restrict__ wih,
                                                  const float* __restrict__ whh,
                                                  unsigned short* __restrict__ bgi,
                                                  unsigned short* __restrict__ bgh,
                                                  const int* __restrict__ rseg,
                                                  int* __restrict__ segstart4,
                                                  float* __restrict__ sums4,
                                                  int* __restrict__ deg4) {
  int b = blockIdx.x;
  if (b < PO0)       inith_body(b, de, hb0);
  else if (b < PO1)  inith0_body(b - PO0, er, h0);
  else if (b < PO2)  relw_body(b - PO1, er, wn, relWb);
  else if (b < PO3)  packb_body(b - PO2, wn, tg, bpack);
  else if (b < PO4)  packgru_body(b - PO3, wih, whh, bgi, bgh);
  else if (b < PO5)  segb_body(b - PO4, rseg, segstart4);
  else if (b < PO6) { int i = (b - PO5) * 256 + threadIdx.x; if (i < TS * R2C * H) sums4[i] = 0.f; }
  else              { int i = (b - PO6) * 256 + threadIdx.x; if (i < TS * NE) deg4[i] = 0; }
}

// ================= CSR build (hist + scans) =================

__global__ void k_hist4(const int* __restrict__ dst, int* __restrict__ deg4) {
  int base = (blockIdx.x * 256 + threadIdx.x) * 4;
  if (base + 3 < TS * EC) {
    int4 d4 = *reinterpret_cast<const int4*>(dst + base);
    int t = base / EC;   // EC%4==0, base%4==0 -> whole quad in one step
    atomicAdd(&deg4[t * NE + d4.x], 1);
    atomicAdd(&deg4[t * NE + d4.y], 1);
    atomicAdd(&deg4[t * NE + d4.z], 1);
    atomicAdd(&deg4[t * NE + d4.w], 1);
  }
}

__global__ __launch_bounds__(256) void k_scan1(const int* __restrict__ deg4,
                                               int* __restrict__ offs4,
                                               int* __restrict__ bsums4) {
  __shared__ int s[256];
  int t = blockIdx.x / NSCAN, blk = blockIdx.x % NSCAN;
  int i = blk * 256 + threadIdx.x;
  int v = (i < NE) ? deg4[t * NE + i] : 0;
  s[threadIdx.x] = v;
  __syncthreads();
  for (int o = 1; o < 256; o <<= 1) {
    int add = (threadIdx.x >= o) ? s[threadIdx.x - o] : 0;
    __syncthreads();
    s[threadIdx.x] += add;
    __syncthreads();
  }
  if (i < NE) offs4[t * (NE + 1) + i] = s[threadIdx.x] - v;  // exclusive
  if (threadIdx.x == 255) bsums4[t * 256 + blk] = s[255];
}

__global__ __launch_bounds__(256) void k_scan2(int* bsums4) {
  __shared__ int s[256];
  int t = blockIdx.x;
  int v = (threadIdx.x < NSCAN) ? bsums4[t * 256 + threadIdx.x] : 0;
  s[threadIdx.x] = v;
  __syncthreads();
  for (int o = 1; o < 256; o <<= 1) {
    int add = (threadIdx.x >= o) ? s[threadIdx.x - o] : 0;
    __syncthreads();
    s[threadIdx.x] += add;
    __syncthreads();
  }
  if (threadIdx.x < NSCAN) bsums4[t * 256 + threadIdx.x] = s[threadIdx.x] - v;  // exclusive
}

__global__ void k_scan3(int* __restrict__ offs4, const int* __restrict__ bsums4,
                        int* __restrict__ cursor4) {
  int t = blockIdx.x / NSCAN, blk = blockIdx.x % NSCAN;
  int i = blk * 256 + threadIdx.x;
  if (i < NE) {
    int o = offs4[t * (NE + 1) + i] + bsums4[t * 256 + blk];
    offs4[t * (NE + 1) + i] = o;
    cursor4[t * NE + i] = o;
  }
  if (blk == 0 && threadIdx.x == 0) offs4[t * (NE + 1) + NE] = EC;
}

// ================= device bodies for fused per-step kernels =================

// dst-range-partitioned scatter for ONE step t (XCD-local writes), block id = b
DEVINL void scatter_body(int b, int t, const int* __restrict__ dst, const int* __restrict__ src,
                         const int* __restrict__ et, int* __restrict__ cursor4,
                         unsigned int* __restrict__ se4) {
  int r = b & (NRNG - 1);
  int chunk = b >> 3;
  int li = chunk * SCHK + threadIdx.x * 4;
  if (li >= EC) return;                     // EC%4==0 so full quad when li<EC
  int base = t * EC + li;
  int4 d4 = *reinterpret_cast<const int4*>(dst + base);
  int4 s4 = *reinterpret_cast<const int4*>(src + base);
  int4 e4 = *reinterpret_cast<const int4*>(et + base);
  int* cur = cursor4 + t * NE;
  unsigned int* se = se4 + (size_t)t * EC;
  if ((unsigned)d4.x / DRNG == (unsigned)r) {
    int p = atomicAdd(&cur[d4.x], 1);
    se[p] = (unsigned int)s4.x | ((unsigned int)e4.x << 16);
  }
  if ((unsigned)d4.y / DRNG == (unsigned)r) {
    int p = atomicAdd(&cur[d4.y], 1);
    se[p] = (unsigned int)s4.y | ((unsigned int)e4.y << 16);
  }
  if ((unsigned)d4.z / DRNG == (unsigned)r) {
    int p = atomicAdd(&cur[d4.z], 1);
    se[p] = (unsigned int)s4.z | ((unsigned int)e4.z << 16);
  }
  if ((unsigned)d4.w / DRNG == (unsigned)r) {
    int p = atomicAdd(&cur[d4.w], 1);
    se[p] = (unsigned int)s4.w | ((unsigned int)e4.w << 16);
  }
}

// segment-sum over sorted rseg, block id = b
DEVINL void relsums_body(int b, const int* __restrict__ rseg, const int* __restrict__ rte,
                         const unsigned short* __restrict__ hb, float* __restrict__ sums) {
  int base = b * RCH;
  int d = threadIdx.x;
  bool act = d < H;
  float a0 = 0.f, a1 = 0.f, a2 = 0.f, a3 = 0.f;
  int prev = rseg[base];
  for (int g = 0; g < RCH; g += 8) {
    int e = base + g;
    int4 sgA = *reinterpret_cast<const int4*>(rseg + e);
    int4 sgB = *reinterpret_cast<const int4*>(rseg + e + 4);
    int4 rrA = *reinterpret_cast<const int4*>(rte + e);
    int4 rrB = *reinterpret_cast<const int4*>(rte + e + 4);
    if (sgB.w == prev) {           // sorted => whole group of 8 in same segment
      if (act) {
        float v0 = u2f(hb[(size_t)rrA.x * KP + d]);
        float v1 = u2f(hb[(size_t)rrA.y * KP + d]);
        float v2 = u2f(hb[(size_t)rrA.z * KP + d]);
        float v3 = u2f(hb[(size_t)rrA.w * KP + d]);
        float v4 = u2f(hb[(size_t)rrB.x * KP + d]);
        float v5 = u2f(hb[(size_t)rrB.y * KP + d]);
        float v6 = u2f(hb[(size_t)rrB.z * KP + d]);
        float v7 = u2f(hb[(size_t)rrB.w * KP + d]);
        a0 += v0; a1 += v1; a2 += v2; a3 += v3;
        a0 += v4; a1 += v5; a2 += v6; a3 += v7;
      }
    } else {                       // boundary group (rare): scalar path
      int ss[8] = {sgA.x, sgA.y, sgA.z, sgA.w, sgB.x, sgB.y, sgB.z, sgB.w};
      int rr[8] = {rrA.x, rrA.y, rrA.z, rrA.w, rrB.x, rrB.y, rrB.z, rrB.w};
      #pragma unroll
      for (int j = 0; j < 8; j++) {
        if (ss[j] != prev) {
          if (act) atomicAdd(&sums[prev * H + d], a0 + a1 + a2 + a3);
          a0 = a1 = a2 = a3 = 0.f;
          prev = ss[j];
        }
        if (act) a0 += u2f(hb[(size_t)rr[j] * KP + d]);
      }
    }
  }
  if (act) atomicAdd(&sums[prev * H + d], a0 + a1 + a2 + a3);
}

// node GEMMs via MFMA, block id = b
DEVINL void gemm_body(int b, const unsigned short* __restrict__ hb,
                      const unsigned short* __restrict__ bpack,
                      const float* __restrict__ tgb,
                      bf16* __restrict__ hWb, bf16* __restrict__ twb) {
  int wid = threadIdx.x >> 6, lane = threadIdx.x & 63;
  int row0 = b * 64 + wid * 16;
  if (row0 >= NE) return;                 // wave-uniform
  int arow = min(row0 + (lane & 15), NE - 1);
  const unsigned short* ap = hb + (size_t)arow * KP + (lane >> 4) * 8;
  bf16x8v a[KS];
  #pragma unroll
  for (int ks = 0; ks < KS; ks++)
    a[ks] = *reinterpret_cast<const bf16x8v*>(ap + ks * 32);

  const unsigned short* b1p = bpack + (size_t)lane * 8;
  const unsigned short* b2p = b1p + (size_t)NT * KS * 64 * 8;
  int colb = lane & 15;
  int rbase = row0 + (lane >> 4) * 4;

  for (int nt = 0; nt < NT; nt++) {
    bf16x8v b1[KS], b2[KS];
    #pragma unroll
    for (int ks = 0; ks < KS; ks++) {
      size_t boff = (size_t)(nt * KS + ks) * 64 * 8;
      b1[ks] = *reinterpret_cast<const bf16x8v*>(b1p + boff);
      b2[ks] = *reinterpret_cast<const bf16x8v*>(b2p + boff);
    }
    f32x4 acc1 = {}, acc2 = {};
    #pragma unroll
    for (int ks = 0; ks < KS; ks++) {
      acc1 = __builtin_amdgcn_mfma_f32_16x16x32_bf16(a[ks], b1[ks], acc1, 0, 0, 0);
      acc2 = __builtin_amdgcn_mfma_f32_16x16x32_bf16(a[ks], b2[ks], acc2, 0, 0, 0);
    }
    int col = nt * 16 + colb;
    bool cok = (col < H);
    float bias = cok ? tgb[col] : 0.f;
    #pragma unroll
    for (int q = 0; q < 4; q++) {
      int row = rbase + q;
      if (cok && row < NE) {
        hWb[(size_t)row * H + col] = f2b(acc1[q]);
        twb[(size_t)row * H + col] = f2b(sigmoidf(acc2[q] + bias));
      }
    }
  }
}

// GRU gates + l2norm for relation r -> h0 (and h0_out when non-null)
DEVINL void grutail_body(int r, const float* __restrict__ gi_ws,
                         const float* __restrict__ gh_ws,
                         const float* __restrict__ b_ih,
                         const float* __restrict__ b_hh,
                         float* __restrict__ h0,
                         float* __restrict__ h0_out) {
  __shared__ float xc[H];
  __shared__ float red[4];
  int tid = threadIdx.x, wid = tid >> 6, lane = tid & 63;
  float ssp = 0.f;
  for (int d = tid; d < H; d += 256) {
    float gir = gi_ws[(size_t)r * GCS + d]         + b_ih[d];
    float ghr = gh_ws[(size_t)r * GCS + d]         + b_hh[d];
    float giz = gi_ws[(size_t)r * GCS + H + d]     + b_ih[H + d];
    float ghz = gh_ws[(size_t)r * GCS + H + d]     + b_hh[H + d];
    float gin = gi_ws[(size_t)r * GCS + 2 * H + d] + b_ih[2 * H + d];
    float ghn = gh_ws[(size_t)r * GCS + 2 * H + d] + b_hh[2 * H + d];
    float rg = sigmoidf(gir + ghr);
    float z  = sigmoidf(giz + ghz);
    float n  = tanhf(gin + rg * ghn);
    float hv = h0[r * H + d];
    float o  = (1.0f - z) * n + z * hv;
    xc[d] = o;
    ssp += o * o;
  }
  ssp = wave_sum(ssp);
  if (lane == 0) red[wid] = ssp;
  __syncthreads();
  float ss = red[0] + red[1] + red[2] + red[3];
  float sc = 1.0f / fmaxf(sqrtf(ss), 1e-12f);
  for (int d = tid; d < H; d += 256) {
    float o = xc[d] * sc;
    h0[r * H + d] = o;
    if (h0_out) h0_out[r * H + d] = o;
  }
}

// aggregate + rrelu + l2norm + time gate + l2norm; reads bf16 state hbcur,
// writes evolve (f32 out) and next step's bf16 state hbnext.
DEVINL void aggfin_body(int b, const int* __restrict__ offs,
                        const unsigned int* __restrict__ se,
                        const bf16* __restrict__ hWb,
                        const unsigned short* __restrict__ relWb,
                        const bf16* __restrict__ twb,
                        const unsigned short* __restrict__ hbcur,
                        float* __restrict__ evolve,
                        unsigned short* __restrict__ hbnext) {
  int wid = threadIdx.x >> 6, lane = threadIdx.x & 63;
  int i = b * 4 + wid;
  if (i >= NE) return;
  int s0 = offs[i], s1 = offs[i + 1];
  int d0 = lane * 4;
  bool act = d0 < H;
  const unsigned short* hw = (const unsigned short*)hWb;
  float a0 = 0.f, a1 = 0.f, a2 = 0.f, a3 = 0.f;

  int p = s0;
  for (; p + 4 <= s1; p += 4) {
    unsigned int e0 = se[p], e1 = se[p + 1], e2 = se[p + 2], e3 = se[p + 3];
    if (act) {
      ushort4 m0 = *reinterpret_cast<const ushort4*>(hw + (size_t)(e0 & 0xFFFFu) * H + d0);
      ushort4 m1 = *reinterpret_cast<const ushort4*>(hw + (size_t)(e1 & 0xFFFFu) * H + d0);
      ushort4 m2 = *reinterpret_cast<const ushort4*>(hw + (size_t)(e2 & 0xFFFFu) * H + d0);
      ushort4 m3 = *reinterpret_cast<const ushort4*>(hw + (size_t)(e3 & 0xFFFFu) * H + d0);
      ushort4 r0 = *reinterpret_cast<const ushort4*>(relWb + (size_t)(e0 >> 16) * H + d0);
      ushort4 r1 = *reinterpret_cast<const ushort4*>(relWb + (size_t)(e1 >> 16) * H + d0);
      ushort4 r2 = *reinterpret_cast<const ushort4*>(relWb + (size_t)(e2 >> 16) * H + d0);
      ushort4 r3 = *reinterpret_cast<const ushort4*>(relWb + (size_t)(e3 >> 16) * H + d0);
      a0 += u2f(m0.x) + u2f(r0.x) + u2f(m1.x) + u2f(r1.x)
          + u2f(m2.x) + u2f(r2.x) + u2f(m3.x) + u2f(r3.x);
      a1 += u2f(m0.y) + u2f(r0.y) + u2f(m1.y) + u2f(r1.y)
          + u2f(m2.y) + u2f(r2.y) + u2f(m3.y) + u2f(r3.y);
      a2 += u2f(m0.z) + u2f(r0.z) + u2f(m1.z) + u2f(r1.z)
          + u2f(m2.z) + u2f(r2.z) + u2f(m3.z) + u2f(r3.z);
      a3 += u2f(m0.w) + u2f(r0.w) + u2f(m1.w) + u2f(r1.w)
          + u2f(m2.w) + u2f(r2.w) + u2f(m3.w) + u2f(r3.w);
    }
  }
  for (; p < s1; p++) {
    unsigned int e0 = se[p];
    if (act) {
      ushort4 m0 = *reinterpret_cast<const ushort4*>(hw + (size_t)(e0 & 0xFFFFu) * H + d0);
      ushort4 r0 = *reinterpret_cast<const ushort4*>(relWb + (size_t)(e0 >> 16) * H + d0);
      a0 += u2f(m0.x) + u2f(r0.x);
      a1 += u2f(m0.y) + u2f(r0.y);
      a2 += u2f(m0.z) + u2f(r0.z);
      a3 += u2f(m0.w) + u2f(r0.w);
    }
  }

  int deg = s1 - s0;
  float nrm = deg > 0 ? 1.0f / (float)deg : 0.0f;
  float c0 = a0 * nrm; c0 = c0 >= 0.f ? c0 : SLOPE * c0;
  float c1 = a1 * nrm; c1 = c1 >= 0.f ? c1 : SLOPE * c1;
  float c2 = a2 * nrm; c2 = c2 >= 0.f ? c2 : SLOPE * c2;
  float c3 = a3 * nrm; c3 = c3 >= 0.f ? c3 : SLOPE * c3;
  float ss = act ? (c0 * c0 + c1 * c1 + c2 * c2 + c3 * c3) : 0.f;
  ss = wave_sum(ss);
  float sc = 1.0f / fmaxf(sqrtf(ss), 1e-12f);
  c0 *= sc; c1 *= sc; c2 *= sc; c3 *= sc;

  // time gate + combine + l2norm (h state read as bf16)
  float v0 = 0.f, v1 = 0.f, v2 = 0.f, v3 = 0.f;
  if (act) {
    ushort4 t4 = *reinterpret_cast<const ushort4*>((const unsigned short*)twb + (size_t)i * H + d0);
    ushort4 h4 = *reinterpret_cast<const ushort4*>(hbcur + (size_t)i * KP + d0);
    float t0 = u2f(t4.x), t1 = u2f(t4.y), t2 = u2f(t4.z), t3 = u2f(t4.w);
    v0 = t0 * c0 + (1.0f - t0) * u2f(h4.x);
    v1 = t1 * c1 + (1.0f - t1) * u2f(h4.y);
    v2 = t2 * c2 + (1.0f - t2) * u2f(h4.z);
    v3 = t3 * c3 + (1.0f - t3) * u2f(h4.w);
  }
  float ss2 = v0 * v0 + v1 * v1 + v2 * v2 + v3 * v3;
  ss2 = wave_sum(ss2);
  float sc2 = 1.0f / fmaxf(sqrtf(ss2), 1e-12f);
  if (act) {
    float4 o = make_float4(v0 * sc2, v1 * sc2, v2 * sc2, v3 * sc2);
    *reinterpret_cast<float4*>(evolve + (size_t)i * H + d0) = o;
    if (hbnext) {
      ushort4 ob; ob.x = f2bu(o.x); ob.y = f2bu(o.y); ob.z = f2bu(o.z); ob.w = f2bu(o.w);
      *reinterpret_cast<ushort4*>(hbnext + (size_t)i * KP + d0) = ob;
    }
  } else if (d0 < KP && hbnext) {
    ushort4 z; z.x = z.y = z.z = z.w = 0;
    *reinterpret_cast<ushort4*>(hbnext + (size_t)i * KP + d0) = z;
  }
}

// GRU A-matrix build, block id = b
DEVINL void a2b_body(int b, const float* __restrict__ er, const float* __restrict__ sums,
                     const int* __restrict__ segstart, const float* __restrict__ h0,
                     unsigned short* __restrict__ xcatb, unsigned short* __restrict__ h0b) {
  int i = b * 256 + threadIdx.x;
  const int n1 = GR * 416;
  if (i < n1) {
    int r = i / 416, c = i % 416;
    float v = 0.f;
    if (r < R2C) {
      if (c < H) v = er[r * H + c];
      else if (c < 2 * H) {
        int cnt = segstart[r + 1] - segstart[r];
        float inv = cnt > 0 ? 1.0f / (float)cnt : 0.0f;
        v = sums[r * H + (c - H)] * inv;
      }
    }
    xcatb[i] = f2bu(v);
  } else {
    int i2 = i - n1;
    if (i2 < GR * 224) {
      int r = i2 / 224, c = i2 % 224;
      float v = (r < R2C && c < H) ? h0[r * H + c] : 0.f;
      h0b[i2] = f2bu(v);
    }
  }
}

// ---------------- fused: node GEMM + relsums + step t's scatter + prev grutail ----------------
__global__ __launch_bounds__(256) void k_rsgemm(int t,
                                                const int* __restrict__ rseg,
                                                const int* __restrict__ rte,
                                                const unsigned short* __restrict__ hb,
                                                float* __restrict__ sums,
                                                const unsigned short* __restrict__ bpack,
                                                const float* __restrict__ tgb,
                                                bf16* __restrict__ hWb,
                                                bf16* __restrict__ twb,
                                                const int* __restrict__ dst,
                                                const int* __restrict__ src,
                                                const int* __restrict__ et,
                                                int* __restrict__ cursor4,
                                                unsigned int* __restrict__ se4,
                                                const float* __restrict__ gi_ws,
                                                const float* __restrict__ gh_ws,
                                                const float* __restrict__ b_ih,
                                                const float* __restrict__ b_hh,
                                                float* __restrict__ h0) {
  int b = blockIdx.x;
  if (b < GB_GEMM)
    gemm_body(b, hb, bpack, tgb, hWb, twb);
  else if (b < GB_GEMM + GB_RELS)
    relsums_body(b - GB_GEMM, rseg, rte, hb, sums);
  else if (b < GB_GEMM + GB_RELS + GSCAT1)
    scatter_body(b - (GB_GEMM + GB_RELS), t, dst, src, et, cursor4, se4);
  else
    grutail_body(b - (GB_GEMM + GB_RELS + GSCAT1), gi_ws, gh_ws, b_ih, b_hh, h0,
                 (float*)nullptr);   // prev step's GRU tail (t>=1 only)
}

// ---------------- fused: aggfin (blocks 0..12499) + a2b (rest) ----------------
__global__ __launch_bounds__(256) void k_afa2b(const int* __restrict__ offs,
                                               const unsigned int* __restrict__ se,
                                               const bf16* __restrict__ hWb,
                                               const unsigned short* __restrict__ relWb,
                                               const bf16* __restrict__ twb,
                                               const unsigned short* __restrict__ hbcur,
                                               float* __restrict__ evolve,
                                               unsigned short* __restrict__ hbnext,
                                               const float* __restrict__ er,
                                               const float* __restrict__ sums,
                                               const int* __restrict__ segstart,
                                               const float* __restrict__ h0,
                                               unsigned short* __restrict__ xcatb,
                                               unsigned short* __restrict__ h0b) {
  if (blockIdx.x < GB_AGG)
    aggfin_body(blockIdx.x, offs, se, hWb, relWb, twb, hbcur, evolve, hbnext);
  else
    a2b_body(blockIdx.x - GB_AGG, er, sums, segstart, h0, xcatb, h0b);
}

// ---------------- per-step: GRU GEMMs via MFMA -> gi, gh [512][608] f32 ----------------
__global__ __launch_bounds__(256) void k_grumm(const unsigned short* __restrict__ xcatb,
                                               const unsigned short* __restrict__ h0b,
                                               const unsigned short* __restrict__ bgi,
                                               const unsigned short* __restrict__ bgh,
                                               float* __restrict__ gi_ws,
                                               float* __restrict__ gh_ws) {
  int wid = threadIdx.x >> 6, lane = threadIdx.x & 63;
  int nt   = blockIdx.x % GNT;
  int row0 = (blockIdx.x / GNT) * 64 + wid * 16;
  int arow = row0 + (lane & 15);

  const unsigned short* api = xcatb + (size_t)arow * 416 + (lane >> 4) * 8;
  bf16x8v ai[GKI];
  #pragma unroll
  for (int ks = 0; ks < GKI; ks++)
    ai[ks] = *reinterpret_cast<const bf16x8v*>(api + ks * 32);
  const unsigned short* aph = h0b + (size_t)arow * 224 + (lane >> 4) * 8;
  bf16x8v ah[GKH];
  #pragma unroll
  for (int ks = 0; ks < GKH; ks++)
    ah[ks] = *reinterpret_cast<const bf16x8v*>(aph + ks * 32);

  const unsigned short* bip = bgi + ((size_t)(nt * GKI) * 64 + lane) * 8;
  bf16x8v bi[GKI];
  #pragma unroll
  for (int ks = 0; ks < GKI; ks++)
    bi[ks] = *reinterpret_cast<const bf16x8v*>(bip + (size_t)ks * 64 * 8);
  const unsigned short* bhp = bgh + ((size_t)(nt * GKH) * 64 + lane) * 8;
  bf16x8v bh[GKH];
  #pragma unroll
  for (int ks = 0; ks < GKH; ks++)
    bh[ks] = *reinterpret_cast<const bf16x8v*>(bhp + (size_t)ks * 64 * 8);

  f32x4 a1 = {}, a2 = {};
  #pragma unroll
  for (int ks = 0; ks < GKI; ks++)
    a1 = __builtin_amdgcn_mfma_f32_16x16x32_bf16(ai[ks], bi[ks], a1, 0, 0, 0);
  #pragma unroll
  for (int ks = 0; ks < GKH; ks++)
    a2 = __builtin_amdgcn_mfma_f32_16x16x32_bf16(ah[ks], bh[ks], a2, 0, 0, 0);

  int col = nt * 16 + (lane & 15);
  int rb = row0 + (lane >> 4) * 4;
  #pragma unroll
  for (int q = 0; q < 4; q++) {
    gi_ws[(size_t)(rb + q) * GCS + col] = a1[q];
    gh_ws[(size_t)(rb + q) * GCS + col] = a2[q];
  }
}

// ---------------- standalone GRU tail (last step only, writes h0out) ----------------
__global__ __launch_bounds__(256) void k_grutail(const float* __restrict__ gi_ws,
                                                 const float* __restrict__ gh_ws,
                                                 const float* __restrict__ b_ih,
                                                 const float* __restrict__ b_hh,
                                                 float* __restrict__ h0,
                                                 float* __restrict__ h0_out) {
  grutail_body(blockIdx.x, gi_ws, gh_ws, b_ih, b_hh, h0, h0_out);
}

extern "C" void kernel_launch(void* const* d_in, const int* in_sizes, int n_in,
                              void* d_out, int out_size, void* d_ws, size_t ws_size,
                              hipStream_t stream) {
  const float* de  = (const float*)d_in[0];
  const float* er  = (const float*)d_in[1];
  const float* wih = (const float*)d_in[2];
  const float* whh = (const float*)d_in[3];
  const float* bih = (const float*)d_in[4];
  const float* bhh = (const float*)d_in[5];
  const float* wn  = (const float*)d_in[6];
  const float* tg  = (const float*)d_in[7];
  const float* tgb = (const float*)d_in[8];
  const int* src  = (const int*)d_in[9];
  const int* dst  = (const int*)d_in[10];
  const int* et   = (const int*)d_in[11];
  const int* rte  = (const int*)d_in[12];
  const int* rseg = (const int*)d_in[13];

  char* w = (char*)d_ws;
  auto alloc = [&](size_t bytes) -> char* {
    char* p = w;
    w += (bytes + 255) / 256 * 256;
    return p;
  };
  unsigned short* hbA = (unsigned short*)alloc(sizeof(unsigned short) * (size_t)NE * KP); // 22.4 MB
  unsigned short* hbB = (unsigned short*)alloc(sizeof(unsigned short) * (size_t)NE * KP); // 22.4 MB
  bf16*  hWb   = (bf16*) alloc(sizeof(bf16)  * (size_t)NE * H);   // 20 MB
  bf16*  twb   = (bf16*) alloc(sizeof(bf16)  * (size_t)NE * H);   // 20 MB
  unsigned short* relWb = (unsigned short*)alloc(sizeof(unsigned short) * R2C * H); // 200 KB
  float* h0    = (float*)alloc(sizeof(float) * R2C * H);
  float* sums4 = (float*)alloc(sizeof(float) * TS * R2C * H);     // 1.6 MB
  unsigned short* bpack = (unsigned short*)alloc(sizeof(unsigned short) * 2 * NT * KS * 64 * 8); // 186 KB
  unsigned short* bgi   = (unsigned short*)alloc(sizeof(unsigned short) * GNT * GKI * 64 * 8);   // 506 KB
  unsigned short* bgh   = (unsigned short*)alloc(sizeof(unsigned short) * GNT * GKH * 64 * 8);   // 272 KB
  unsigned short* xcatb = (unsigned short*)alloc(sizeof(unsigned short) * GR * 416);             // 416 KB
  unsigned short* h0b   = (unsigned short*)alloc(sizeof(unsigned short) * GR * 224);             // 224 KB
  float* gi_ws = (float*)alloc(sizeof(float) * GR * GCS);          // 1.24 MB
  float* gh_ws = (float*)alloc(sizeof(float) * GR * GCS);          // 1.24 MB
  int* segstart4 = (int*)alloc(sizeof(int) * TS * (R2C + 1));
  int* deg4    = (int*) alloc(sizeof(int) * TS * NE);              // 800 KB
  int* offs4   = (int*) alloc(sizeof(int) * TS * (NE + 1));        // 800 KB
  int* cursor4 = (int*) alloc(sizeof(int) * TS * NE);              // 800 KB
  unsigned int* se4 = (unsigned int*)alloc(sizeof(unsigned int) * (size_t)TS * EC); // 6.4 MB
  int* bsums4  = (int*) alloc(sizeof(int) * TS * 256);
  (void)ws_size; (void)in_sizes; (void)n_in; (void)out_size;

  float* out    = (float*)d_out;
  float* evolve = out;                       // [TS, NE, H]
  float* h0out  = out + (size_t)TS * NE * H; // [R2C, H]

  const int gGru   = 8 * GNT;                              // 304
  const int gE4i   = (TS * EC / 4 + 255) / 256;            // 1563

  // ---- prologue: fused setup + CSR scan chain ----
  k_prologue<<<PO7, 256, 0, stream>>>(de, hbA, er, h0,
                                      wn, relWb, tg, bpack, wih, whh, bgi, bgh,
                                      rseg, segstart4, sums4, deg4);
  k_hist4<<<gE4i, 256, 0, stream>>>(dst, deg4);
  k_scan1<<<TS * NSCAN, 256, 0, stream>>>(deg4, offs4, bsums4);
  k_scan2<<<TS, 256, 0, stream>>>(bsums4);
  k_scan3<<<TS * NSCAN, 256, 0, stream>>>(offs4, bsums4, cursor4);

  for (int t = 0; t < TS; t++) {
    const int* rseg_t = rseg + (size_t)t * EC;
    const int* rte_t  = rte  + (size_t)t * EC;
    float* sums_t = sums4 + (size_t)t * R2C * H;
    float* evo_t = evolve + (size_t)t * NE * H;
    unsigned short* hbcur  = (t & 1) ? hbB : hbA;
    unsigned short* hbnext = (t < TS - 1) ? ((t & 1) ? hbA : hbB)
                                          : (unsigned short*)nullptr;

    // fused: node GEMM (MFMA) ∥ relsums ∥ step t's CSR scatter ∥ prev GRU tail
    int nblk = GB_GEMM + GB_RELS + GSCAT1 + (t > 0 ? R2C : 0);
    k_rsgemm<<<nblk, 256, 0, stream>>>(
        t, rseg_t, rte_t, hbcur, sums_t, bpack, tgb, hWb, twb,
        dst, src, et, cursor4, se4, gi_ws, gh_ws, bih, bhh, h0);

    // fused: aggregate+timegate (reads hbcur, writes evolve[t], hbnext) ∥ GRU A-build
    k_afa2b<<<GB_AGG + GB_A2B, 256, 0, stream>>>(offs4 + t * (NE + 1), se4 + (size_t)t * EC,
                                                 hWb, relWb, twb, hbcur, evo_t, hbnext,
                                                 er, sums_t, segstart4 + t * (R2C + 1),
                                                 h0, xcatb, h0b);

    // GRU GEMMs (gates applied by next step's rsgemm, or the final grutail)
    k_grumm<<<gGru, 256, 0, stream>>>(xcatb, h0b, bgi, bgh, gi_ws, gh_ws);
  }

  // final GRU tail: updates h0 and writes h0out
  k_grutail<<<R2C, 256, 0, stream>>>(gi_ws, gh_ws, bih, bhh, h0, h0out);
}